// Round 9
// baseline (567.700 us; speedup 1.0000x reference)
//
#include <hip/hip_runtime.h>
#include <hip/hip_fp16.h>
#include <math.h>

static constexpr int N  = 50000;
static constexpr int E  = 800000;
static constexpr int G  = 512;
static constexpr int D  = 128;
static constexpr int EF = 8;
static constexpr int EE = 64;
static constexpr int L  = 4;
static constexpr int NC = 10;

typedef _Float16 half8 __attribute__((ext_vector_type(8)));
typedef _Float16 h2v  __attribute__((ext_vector_type(2)));
typedef float f2v __attribute__((ext_vector_type(2)));
typedef float f32x4 __attribute__((ext_vector_type(4)));

union H4 { float4 f4; f32x4 v4; h2v h[4]; };

#if __has_builtin(__builtin_amdgcn_fdot2)
#define FDOT2(a, b, c) __builtin_amdgcn_fdot2((a), (b), (c), false)
#else
#define FDOT2(a, b, c) ((float)(a)[0]*(float)(b)[0] + (float)(a)[1]*(float)(b)[1] + (c))
#endif

__device__ __forceinline__ h2v pkrtz(float a, float b) {
    return (h2v)__builtin_amdgcn_cvt_pkrtz(a, b);
}
__device__ __forceinline__ h2v hmax2(h2v a, h2v b) {
#if __has_builtin(__builtin_elementwise_max)
    return __builtin_elementwise_max(a, b);
#else
    h2v r; r[0] = a[0] > b[0] ? a[0] : b[0]; r[1] = a[1] > b[1] ? a[1] : b[1]; return r;
#endif
}
__device__ __forceinline__ h2v hfma2(h2v a, h2v b, h2v c) {
#if __has_builtin(__builtin_elementwise_fma)
    return __builtin_elementwise_fma(a, b, c);
#else
    return a * b + c;
#endif
}
// sum over 8-lane head group (lanes t, t^1, t^2, t^4) via DPP — no LDS traffic
__device__ __forceinline__ float red8(float v) {
#if __has_builtin(__builtin_amdgcn_update_dpp)
    v += __builtin_bit_cast(float, __builtin_amdgcn_update_dpp(
            0, __builtin_bit_cast(int, v), 0xB1, 0xF, 0xF, true));   // quad_perm xor1
    v += __builtin_bit_cast(float, __builtin_amdgcn_update_dpp(
            0, __builtin_bit_cast(int, v), 0x4E, 0xF, 0xF, true));   // quad_perm xor2
    v += __builtin_bit_cast(float, __builtin_amdgcn_update_dpp(
            0, __builtin_bit_cast(int, v), 0x141, 0xF, 0xF, true));  // row_half_mirror
#else
    v += __shfl_xor(v, 1); v += __shfl_xor(v, 2); v += __shfl_xor(v, 4);
#endif
    return v;
}

#define LOG2E 1.44269504088896340736f

static constexpr size_t pad64(size_t w){ return (w + 63) & ~size_t(63); }
// workspace layout in 4-byte words; [0, ZERO_END) is zero-initialized by prep
static constexpr size_t O_CNT     = 0;                               // N ints
static constexpr size_t O_CURSOR  = O_CNT + pad64(N);                // N ints
static constexpr size_t ZERO_END  = O_CURSOR + pad64(N);
static constexpr size_t O_CSROFF  = ZERO_END;                        // N+1 ints
static constexpr size_t O_BSUM    = O_CSROFF + pad64(N+1);           // 64 ints
static constexpr size_t O_CSRSRC  = O_BSUM + 64;                     // E ints (row BYTE offsets)
static constexpr size_t O_CSREA   = O_CSRSRC + pad64(E);             // E*8 halfs = E*4 words
static constexpr size_t O_MH      = O_CSREA + pad64((size_t)E*4);    // L*D*8 halfs
static constexpr size_t O_CFOLD   = O_MH + pad64((size_t)L*512);     // L*D f32
static constexpr size_t O_LOOPM   = O_CFOLD + pad64(L*D);            // N*8 halfs
static constexpr size_t O_SELFF   = O_LOOPM + pad64((size_t)N*4);    // N f32
static constexpr size_t O_WFRAG   = O_SELFF + pad64(N);              // L*32768 halfs
static constexpr size_t O_XH      = O_WFRAG + pad64((size_t)L*16384);// N*D halfs
static constexpr size_t O_XLH     = O_XH  + pad64((size_t)N*64);
static constexpr size_t O_XRH     = O_XLH + pad64((size_t)N*64);

// prep grid partition (256-thread blocks)
static constexpr int PB_EMB  = (N * D) / 256;                 // 25000
static constexpr int PB_ZERO = ((int)ZERO_END + 255) / 256;
static constexpr int PB_WCVT = (L * 32768) / 256;             // 512
static constexpr int PB_FOLD = L;                             // 4
static constexpr int PB_TOTAL = PB_EMB + PB_ZERO + PB_WCVT + PB_FOLD;

// fused: embed (fp16) | zero | wcvt (fragment-ordered weights) | fold (edge proj fold, fp16)
__global__ __launch_bounds__(256) void prep_kernel(
        const int* __restrict__ xn, const float* __restrict__ emb, __half* __restrict__ xh,
        float* __restrict__ zbase,
        const float* __restrict__ Wl, const float* __restrict__ Wr, _Float16* __restrict__ wfrag,
        const float* __restrict__ edge_W, const float* __restrict__ edge_b,
        const float* __restrict__ We, _Float16* __restrict__ Mh, float* __restrict__ cfold) {
    int bid = blockIdx.x, t = threadIdx.x;
    if (bid < PB_EMB) {
        int i = bid * 256 + t;                     // N*D
        int n = i >> 7, c = i & 127;
        xh[i] = __float2half_rn(emb[xn[n] * D + c]);
    } else if (bid < PB_EMB + PB_ZERO) {
        int i = (bid - PB_EMB) * 256 + t;
        if (i < (int)ZERO_END) zbase[i] = 0.0f;
    } else if (bid < PB_EMB + PB_ZERO + PB_WCVT) {
        int i = (bid - PB_EMB - PB_ZERO) * 256 + t; // L*32768
        int j    = i & 7;
        int lane = (i >> 3) & 63;
        int nt   = (i >> 9) & 15;
        int kt   = (i >> 13) & 3;
        int l    = i >> 15;
        int k = kt * 32 + (lane >> 4) * 8 + j;
        int n = nt * 16 + (lane & 15);
        float v = (n < 128) ? Wl[((size_t)l * D + k) * D + n]
                            : Wr[((size_t)l * D + k) * D + (n - 128)];
        wfrag[i] = (_Float16)v;
    } else {
        int l = bid - PB_EMB - PB_ZERO - PB_WCVT;  // 4 blocks
        if (t >= 128) return;
        const float* Wel = We + (size_t)l * EE * D;
        for (int j = 0; j < EF; ++j) {
            float s = 0.f;
            for (int k = 0; k < EE; ++k) s += edge_W[j * EE + k] * Wel[k * D + t];
            Mh[((size_t)l * D + t) * 8 + j] = (_Float16)s;   // [l][c][j]
        }
        float s = 0.f;
        for (int k = 0; k < EE; ++k) s += edge_b[k] * Wel[k * D + t];
        cfold[l * D + t] = s;
    }
}

__global__ void edge_cnt_kernel(const int* __restrict__ src, const int* __restrict__ dst,
                                int* __restrict__ cnt) {
    int e = blockIdx.x * blockDim.x + threadIdx.x;
    if (e >= E) return;
    if (src[e] != dst[e]) atomicAdd(&cnt[dst[e]], 1);
}

__global__ void scan1_kernel(const int* __restrict__ cnt, int* __restrict__ out /*=csr_off+1*/,
                             int* __restrict__ bsum) {
    __shared__ int lds[256];
    int b = blockIdx.x, t = threadIdx.x;
    int base = b * 1024 + t * 4;
    int v[4]; int s = 0;
    #pragma unroll
    for (int k = 0; k < 4; ++k) { int idx = base + k; v[k] = (idx < N) ? cnt[idx] : 0; s += v[k]; }
    lds[t] = s; __syncthreads();
    for (int off = 1; off < 256; off <<= 1) {
        int add = (t >= off) ? lds[t - off] : 0;
        __syncthreads();
        lds[t] += add;
        __syncthreads();
    }
    int run = (t > 0) ? lds[t - 1] : 0;
    #pragma unroll
    for (int k = 0; k < 4; ++k) { run += v[k]; int idx = base + k; if (idx < N) out[idx] = run; }
    if (t == 255) bsum[b] = lds[255];
}

__global__ void scan3_kernel(int* __restrict__ csr_off, const int* __restrict__ bsum) {
    int i = blockIdx.x * blockDim.x + threadIdx.x;
    if (i == 0) csr_off[0] = 0;
    if (i >= N) return;
    int b = i >> 10;
    int add = 0;
    for (int k = 0; k < b; ++k) add += bsum[k];
    csr_off[1 + i] += add;
}

// CSR fill: scattered records written non-temporal (re-read a kernel later; keep out of L2)
__global__ void csr_fill_kernel(const int* __restrict__ src, const int* __restrict__ dst,
                                const float* __restrict__ eattr,
                                const int* __restrict__ csr_off, int* __restrict__ cursor,
                                int* __restrict__ csr_src, __half* __restrict__ csr_ea) {
    int e = blockIdx.x * blockDim.x + threadIdx.x;
    if (e >= E) return;
    int s = src[e], d = dst[e];
    if (s == d) return;
    int pos = csr_off[d] + atomicAdd(&cursor[d], 1);
    __builtin_nontemporal_store(s << 8, csr_src + pos);   // byte offset of row s
    const float4* p = reinterpret_cast<const float4*>(eattr + (size_t)e * 8);
    float4 a = p[0], b = p[1];
    H4 h;
    h.h[0] = pkrtz(a.x, a.y); h.h[1] = pkrtz(a.z, a.w);
    h.h[2] = pkrtz(b.x, b.y); h.h[3] = pkrtz(b.z, b.w);
    __builtin_nontemporal_store(h.v4, reinterpret_cast<f32x4*>(csr_ea + (size_t)pos * 8));
}

__global__ void loopmean_kernel(const int* __restrict__ csr_off, const __half* __restrict__ csr_ea,
                                __half* __restrict__ loopm, float* __restrict__ selff) {
    int i = blockIdx.x * blockDim.x + threadIdx.x;   // N*8
    int n = i >> 3, j = i & 7;
    if (n >= N) return;
    int beg = csr_off[n], end = csr_off[n + 1];
    float s = 0.f;
    for (int idx = beg; idx < end; ++idx) s += __half2float(csr_ea[(size_t)idx * 8 + j]);
    int c = end - beg;
    loopm[(size_t)n * 8 + j] = __float2half_rn(s / (float)(c > 1 ? c : 1));
    if (j == 0) selff[n] = (c > 0) ? 1.0f : 0.0f;
}

// [xl|xr] = x @ [Wl|Wr] + [bl|br] via f16 MFMA. Block=256 (4 waves), 16 nodes/block.
__global__ __launch_bounds__(256) void transform_kernel(
        const __half* __restrict__ xh, const _Float16* __restrict__ wfrag,
        const float* __restrict__ bl, const float* __restrict__ br,
        __half* __restrict__ xl_h, __half* __restrict__ xr_h) {
    int w = threadIdx.x >> 6, lane = threadIdx.x & 63;
    int quad = lane >> 4, r16 = lane & 15;
    int m0 = blockIdx.x * 16;
    const _Float16* xrow = reinterpret_cast<const _Float16*>(xh) + (size_t)(m0 + r16) * D + quad * 8;
    half8 a[4];
    #pragma unroll
    for (int kt = 0; kt < 4; ++kt) a[kt] = *reinterpret_cast<const half8*>(xrow + kt * 32);
    f32x4 acc[4];
    #pragma unroll
    for (int nt = 0; nt < 4; ++nt) { f32x4 z = {0.f, 0.f, 0.f, 0.f}; acc[nt] = z; }
    #pragma unroll
    for (int nt = 0; nt < 4; ++nt) {
        int ntile = w * 4 + nt;
        #pragma unroll
        for (int kt = 0; kt < 4; ++kt) {
            half8 b = *reinterpret_cast<const half8*>(
                wfrag + ((size_t)(kt * 16 + ntile) * 64 + lane) * 8);
            acc[nt] = __builtin_amdgcn_mfma_f32_16x16x32_f16(a[kt], b, acc[nt], 0, 0, 0);
        }
    }
    #pragma unroll
    for (int nt = 0; nt < 4; ++nt) {
        int n = (w * 4 + nt) * 16 + r16;
        float bias = (n < 128) ? bl[n] : br[n - 128];
        #pragma unroll
        for (int r = 0; r < 4; ++r) {
            int node = m0 + quad * 4 + r;
            float v = acc[nt][r] + bias;
            if (n < 128) xl_h[(size_t)node * D + n] = __float2half_rn(v);
            else         xr_h[(size_t)node * D + (n - 128)] = __float2half_rn(v);
        }
    }
}

// One wave per node (2 nodes / 128-block). Thread = 2 channels (packed fp16 math).
// Projection in f32 fdot2, z/leaky/logit in pk-f16, exp2 domain, fp16 packed acc, DPP reduce.
__global__ __launch_bounds__(128) void aggregate_kernel(
        const __half* __restrict__ xl_h, const __half* __restrict__ xr_h,
        const __half* __restrict__ loopm, const float* __restrict__ selff,
        const int* __restrict__ csr_off, const int* __restrict__ csr_src,
        const __half* __restrict__ csr_ea,
        const _Float16* __restrict__ Mh, const float* __restrict__ cfold,
        const float* __restrict__ att, const float* __restrict__ gbias,
        const float* __restrict__ bn_gamma, const float* __restrict__ bn_beta,
        __half* __restrict__ xout) {
    int n = blockIdx.x * 2 + (threadIdx.x >> 6);
    int t = threadIdx.x & 63;        // lane in wave
    int c0 = t * 2;                  // channels c0, c0+1; head = t>>3 (8 lanes/head)
    const char* xlb = reinterpret_cast<const char*>(xl_h);
    int lb = t << 2;                 // lane byte offset within a row (2 ch * 2 B)
    h2v attp = pkrtz(att[c0] * LOG2E, att[c0 + 1] * LOG2E);
    H4 m0u, m1u;
    m0u.f4 = *reinterpret_cast<const float4*>(Mh + (size_t)c0 * 8);
    m1u.f4 = *reinterpret_cast<const float4*>(Mh + (size_t)(c0 + 1) * 8);
    float cf0 = cfold[c0], cf1 = cfold[c0 + 1];
    h2v xrp = *reinterpret_cast<const h2v*>(xr_h + (size_t)n * D + c0);
    h2v xlp = *reinterpret_cast<const h2v*>(xl_h + (size_t)n * D + c0);
    const h2v c02 = {(_Float16)0.2f, (_Float16)0.2f};

    // self loop (edge attr = per-node mean of incoming raw attrs, fp16)
    H4 lau;
    lau.f4 = *reinterpret_cast<const float4*>(loopm + (size_t)n * 8);
    float sf = selff[n];
    float ep0 = cf0 * sf, ep1 = cf1 * sf;
    #pragma unroll
    for (int k = 0; k < 4; ++k) { ep0 = FDOT2(lau.h[k], m0u.h[k], ep0); ep1 = FDOT2(lau.h[k], m1u.h[k], ep1); }
    {
        f2v xlf = __builtin_convertvector(xlp, f2v);
        f2v xrf = __builtin_convertvector(xrp, f2v);
        float z0 = xlf[0] + xrf[0] + ep0; z0 = fmaxf(z0, 0.2f * z0);
        float z1 = xlf[1] + xrf[1] + ep1; z1 = fmaxf(z1, 0.2f * z1);
        ep0 = FDOT2(pkrtz(z0, z1), attp, 0.0f);
    }
    float m = red8(ep0);
    float denom = 1.0f;
    h2v acc = xlp;

    int beg = csr_off[n], end = csr_off[n + 1];
    for (int base = beg; base < end; base += 64) {
        int cnt = end - base; if (cnt > 64) cnt = 64;
        int sreg = (t < cnt) ? csr_src[base + t] : 0;   // coalesced; byte row offsets
        int i = 0;
        for (; i + 4 <= cnt; i += 4) {
            int o0 = __shfl(sreg, i),     o1 = __shfl(sreg, i + 1);
            int o2 = __shfl(sreg, i + 2), o3 = __shfl(sreg, i + 3);
            h2v g0 = *reinterpret_cast<const h2v*>(xlb + o0 + lb);
            h2v g1 = *reinterpret_cast<const h2v*>(xlb + o1 + lb);
            h2v g2 = *reinterpret_cast<const h2v*>(xlb + o2 + lb);
            h2v g3 = *reinterpret_cast<const h2v*>(xlb + o3 + lb);
            H4 e0u, e1u, e2u, e3u;
            e0u.f4 = *reinterpret_cast<const float4*>(csr_ea + (size_t)(base + i) * 8);
            e1u.f4 = *reinterpret_cast<const float4*>(csr_ea + (size_t)(base + i) * 8 + 8);
            e2u.f4 = *reinterpret_cast<const float4*>(csr_ea + (size_t)(base + i) * 8 + 16);
            e3u.f4 = *reinterpret_cast<const float4*>(csr_ea + (size_t)(base + i) * 8 + 24);
            float p00 = cf0, p01 = cf1, p10 = cf0, p11 = cf1;
            float p20 = cf0, p21 = cf1, p30 = cf0, p31 = cf1;
            #pragma unroll
            for (int k = 0; k < 4; ++k) {
                p00 = FDOT2(e0u.h[k], m0u.h[k], p00); p01 = FDOT2(e0u.h[k], m1u.h[k], p01);
                p10 = FDOT2(e1u.h[k], m0u.h[k], p10); p11 = FDOT2(e1u.h[k], m1u.h[k], p11);
                p20 = FDOT2(e2u.h[k], m0u.h[k], p20); p21 = FDOT2(e2u.h[k], m1u.h[k], p21);
                p30 = FDOT2(e3u.h[k], m0u.h[k], p30); p31 = FDOT2(e3u.h[k], m1u.h[k], p31);
            }
            h2v z0 = g0 + xrp + pkrtz(p00, p01);
            h2v z1 = g1 + xrp + pkrtz(p10, p11);
            h2v z2 = g2 + xrp + pkrtz(p20, p21);
            h2v z3 = g3 + xrp + pkrtz(p30, p31);
            z0 = hmax2(z0, z0 * c02); z1 = hmax2(z1, z1 * c02);
            z2 = hmax2(z2, z2 * c02); z3 = hmax2(z3, z3 * c02);
            float l0 = red8(FDOT2(z0, attp, 0.0f));
            float l1 = red8(FDOT2(z1, attp, 0.0f));
            float l2 = red8(FDOT2(z2, attp, 0.0f));
            float l3 = red8(FDOT2(z3, attp, 0.0f));
            float gm = fmaxf(fmaxf(l0, l1), fmaxf(l2, l3));
            float nm = fmaxf(m, gm);
            float wo = __builtin_amdgcn_exp2f(m - nm);
            float w0 = __builtin_amdgcn_exp2f(l0 - nm);
            float w1 = __builtin_amdgcn_exp2f(l1 - nm);
            float w2 = __builtin_amdgcn_exp2f(l2 - nm);
            float w3 = __builtin_amdgcn_exp2f(l3 - nm);
            denom = denom * wo + (w0 + w1) + (w2 + w3);
            acc = acc * pkrtz(wo, wo);
            acc = hfma2(pkrtz(w0, w0), g0, acc);
            acc = hfma2(pkrtz(w1, w1), g1, acc);
            acc = hfma2(pkrtz(w2, w2), g2, acc);
            acc = hfma2(pkrtz(w3, w3), g3, acc);
            m = nm;
        }
        for (; i < cnt; ++i) {
            int o0 = __shfl(sreg, i);
            h2v g0 = *reinterpret_cast<const h2v*>(xlb + o0 + lb);
            H4 e0u;
            e0u.f4 = *reinterpret_cast<const float4*>(csr_ea + (size_t)(base + i) * 8);
            float p00 = cf0, p01 = cf1;
            #pragma unroll
            for (int k = 0; k < 4; ++k) { p00 = FDOT2(e0u.h[k], m0u.h[k], p00); p01 = FDOT2(e0u.h[k], m1u.h[k], p01); }
            h2v z0 = g0 + xrp + pkrtz(p00, p01);
            z0 = hmax2(z0, z0 * c02);
            float l0 = red8(FDOT2(z0, attp, 0.0f));
            float nm = fmaxf(m, l0);
            float wo = __builtin_amdgcn_exp2f(m - nm);
            float w0 = __builtin_amdgcn_exp2f(l0 - nm);
            denom = denom * wo + w0;
            acc = acc * pkrtz(wo, wo);
            acc = hfma2(pkrtz(w0, w0), g0, acc);
            m = nm;
        }
    }
    f2v accf = __builtin_convertvector(acc, f2v);
    float inv = 1.0f / denom;
    float h0 = accf[0] * inv + gbias[c0];
    float h1 = accf[1] * inv + gbias[c0 + 1];
    h0 = bn_gamma[c0] * h0 * 0.999995000037499813f + bn_beta[c0];
    h1 = bn_gamma[c0 + 1] * h1 * 0.999995000037499813f + bn_beta[c0 + 1];
    h0 = h0 > 0.f ? h0 : (__expf(h0) - 1.0f);
    h1 = h1 > 0.f ? h1 : (__expf(h1) - 1.0f);
    *reinterpret_cast<__half2*>(xout + (size_t)n * D + c0) = __floats2half2_rn(h0, h1);
}

__device__ __forceinline__ int lower_bound_dev(const int* a, int n, int v) {
    int lo = 0, hi = n;
    while (lo < hi) { int mid = (lo + hi) >> 1; if (a[mid] < v) lo = mid + 1; else hi = mid; }
    return lo;
}

__global__ __launch_bounds__(128) void headpool_kernel(
        const __half* __restrict__ xh, const int* __restrict__ batch,
        const float* __restrict__ hW, const float* __restrict__ hb,
        float* __restrict__ out) {
    __shared__ float lds[128];
    int g = blockIdx.x, t = threadIdx.x;
    int lo = lower_bound_dev(batch, N, g);
    int hi = lower_bound_dev(batch, N, g + 1);
    float s = 0.f;
    #pragma unroll 4
    for (int i = lo; i < hi; ++i) s += __half2float(xh[(size_t)i * D + t]);
    int c = hi - lo;
    lds[t] = s / (float)(c > 1 ? c : 1);
    __syncthreads();
    if (t < NC) {
        float p = hb[t];
        #pragma unroll 8
        for (int cc = 0; cc < D; ++cc) p += lds[cc] * hW[cc * NC + t];
        out[g * NC + t] = p;
    }
}

extern "C" void kernel_launch(void* const* d_in, const int* in_sizes, int n_in,
                              void* d_out, int out_size, void* d_ws, size_t ws_size,
                              hipStream_t stream) {
    const int*   x_nodes   = (const int*)  d_in[0];
    const int*   edge_src  = (const int*)  d_in[1];
    const int*   edge_dst  = (const int*)  d_in[2];
    const float* edge_attr = (const float*)d_in[3];
    const int*   batch     = (const int*)  d_in[4];
    const float* node_emb  = (const float*)d_in[5];
    const float* edge_W    = (const float*)d_in[6];
    const float* edge_b    = (const float*)d_in[7];
    const float* Wl        = (const float*)d_in[8];
    const float* bl        = (const float*)d_in[9];
    const float* Wr        = (const float*)d_in[10];
    const float* br        = (const float*)d_in[11];
    const float* We        = (const float*)d_in[12];
    const float* att       = (const float*)d_in[13];
    const float* gbias     = (const float*)d_in[14];
    const float* bn_gamma  = (const float*)d_in[15];
    const float* bn_beta   = (const float*)d_in[16];
    const float* head_W    = (const float*)d_in[17];
    const float* head_b    = (const float*)d_in[18];
    float* out = (float*)d_out;

    float* ws = (float*)d_ws;
    int*    cnt      = (int*)(ws + O_CNT);
    int*    cursor   = (int*)(ws + O_CURSOR);
    int*    csr_off  = (int*)(ws + O_CSROFF);
    int*    bsum     = (int*)(ws + O_BSUM);
    int*    csr_src  = (int*)(ws + O_CSRSRC);
    __half* csr_ea   = (__half*)(ws + O_CSREA);
    _Float16* Mh     = (_Float16*)(ws + O_MH);
    float*  cfold    = ws + O_CFOLD;
    __half* loopm    = (__half*)(ws + O_LOOPM);
    float*  selff    = ws + O_SELFF;
    _Float16* wfrag  = (_Float16*)(ws + O_WFRAG);
    __half* xh   = (__half*)(ws + O_XH);
    __half* xl_h = (__half*)(ws + O_XLH);
    __half* xr_h = (__half*)(ws + O_XRH);

    prep_kernel<<<PB_TOTAL, 256, 0, stream>>>(x_nodes, node_emb, xh, ws,
                                              Wl, Wr, wfrag, edge_W, edge_b, We, Mh, cfold);
    edge_cnt_kernel<<<(E + 255) / 256, 256, 0, stream>>>(edge_src, edge_dst, cnt);
    {
        int nb = (N + 1023) / 1024;   // 49
        scan1_kernel<<<nb, 256, 0, stream>>>(cnt, csr_off + 1, bsum);
        scan3_kernel<<<(N + 255) / 256, 256, 0, stream>>>(csr_off, bsum);
    }
    csr_fill_kernel<<<(E + 255) / 256, 256, 0, stream>>>(edge_src, edge_dst, edge_attr,
                                                         csr_off, cursor, csr_src, csr_ea);
    loopmean_kernel<<<(N * 8 + 255) / 256, 256, 0, stream>>>(csr_off, csr_ea, loopm, selff);
    for (int l = 0; l < L; ++l) {
        transform_kernel<<<N / 16, 256, 0, stream>>>(
            xh, wfrag + (size_t)l * 32768, bl + l * D, br + l * D, xl_h, xr_h);
        aggregate_kernel<<<N / 2, 128, 0, stream>>>(
            xl_h, xr_h, loopm, selff, csr_off, csr_src, csr_ea,
            Mh + (size_t)l * D * 8, cfold + l * D, att + l * D, gbias + l * D,
            bn_gamma + l * D, bn_beta + l * D, xh);
    }
    headpool_kernel<<<G, 128, 0, stream>>>(xh, batch, head_W, head_b, out);

    (void)in_sizes; (void)n_in; (void)out_size; (void)ws_size;
}

// Round 10
// 538.103 us; speedup vs baseline: 1.0550x; 1.0550x over previous
//
#include <hip/hip_runtime.h>
#include <hip/hip_fp16.h>
#include <math.h>

static constexpr int N  = 50000;
static constexpr int E  = 800000;
static constexpr int G  = 512;
static constexpr int D  = 128;
static constexpr int EF = 8;
static constexpr int EE = 64;
static constexpr int L  = 4;
static constexpr int NC = 10;

typedef _Float16 half8 __attribute__((ext_vector_type(8)));
typedef _Float16 h2v  __attribute__((ext_vector_type(2)));
typedef float f2v __attribute__((ext_vector_type(2)));
typedef float f32x4 __attribute__((ext_vector_type(4)));

union H4 { float4 f4; f32x4 v4; h2v h[4]; };

#if __has_builtin(__builtin_amdgcn_fdot2)
#define FDOT2(a, b, c) __builtin_amdgcn_fdot2((a), (b), (c), false)
#else
#define FDOT2(a, b, c) ((float)(a)[0]*(float)(b)[0] + (float)(a)[1]*(float)(b)[1] + (c))
#endif

__device__ __forceinline__ h2v pkrtz(float a, float b) {
    return (h2v)__builtin_amdgcn_cvt_pkrtz(a, b);
}
__device__ __forceinline__ h2v hmax2(h2v a, h2v b) {
#if __has_builtin(__builtin_elementwise_max)
    return __builtin_elementwise_max(a, b);
#else
    h2v r; r[0] = a[0] > b[0] ? a[0] : b[0]; r[1] = a[1] > b[1] ? a[1] : b[1]; return r;
#endif
}
__device__ __forceinline__ h2v hfma2(h2v a, h2v b, h2v c) {
#if __has_builtin(__builtin_elementwise_fma)
    return __builtin_elementwise_fma(a, b, c);
#else
    return a * b + c;
#endif
}
// sum over 8-lane head group (lanes t, t^1, t^2, t^4) via DPP — no LDS traffic
__device__ __forceinline__ float red8(float v) {
#if __has_builtin(__builtin_amdgcn_update_dpp)
    v += __builtin_bit_cast(float, __builtin_amdgcn_update_dpp(
            0, __builtin_bit_cast(int, v), 0xB1, 0xF, 0xF, true));   // quad_perm xor1
    v += __builtin_bit_cast(float, __builtin_amdgcn_update_dpp(
            0, __builtin_bit_cast(int, v), 0x4E, 0xF, 0xF, true));   // quad_perm xor2
    v += __builtin_bit_cast(float, __builtin_amdgcn_update_dpp(
            0, __builtin_bit_cast(int, v), 0x141, 0xF, 0xF, true));  // row_half_mirror
#else
    v += __shfl_xor(v, 1); v += __shfl_xor(v, 2); v += __shfl_xor(v, 4);
#endif
    return v;
}

#define LOG2E 1.44269504088896340736f

static constexpr size_t pad64(size_t w){ return (w + 63) & ~size_t(63); }
// workspace layout in 4-byte words; [0, ZERO_END) is zero-initialized by prep
static constexpr size_t O_CNT     = 0;                               // N ints
static constexpr size_t ZERO_END  = pad64(N);
static constexpr size_t O_CSROFF  = ZERO_END;                        // N+1 ints
static constexpr size_t O_BSUM    = O_CSROFF + pad64(N+1);           // 64 ints
static constexpr size_t O_MYOFF   = O_BSUM + 64;                     // E ints
static constexpr size_t O_RANK    = O_MYOFF + pad64(E);              // E ints
static constexpr size_t O_CSRSRC  = O_RANK + pad64(E);               // E ints (row BYTE offsets)
static constexpr size_t O_CSREA   = O_CSRSRC + pad64(E);             // E*8 halfs = E*4 words
static constexpr size_t O_MH      = O_CSREA + pad64((size_t)E*4);    // L*D*8 halfs
static constexpr size_t O_CFOLD   = O_MH + pad64((size_t)L*512);     // L*D f32
static constexpr size_t O_LOOPM   = O_CFOLD + pad64(L*D);            // N*8 halfs
static constexpr size_t O_SELFF   = O_LOOPM + pad64((size_t)N*4);    // N f32
static constexpr size_t O_WFRAG   = O_SELFF + pad64(N);              // L*32768 halfs
static constexpr size_t O_XH      = O_WFRAG + pad64((size_t)L*16384);// N*D halfs
static constexpr size_t O_XLH     = O_XH  + pad64((size_t)N*64);
static constexpr size_t O_XRH     = O_XLH + pad64((size_t)N*64);

// prep grid partition (256-thread blocks)
static constexpr int PB_EMB  = (N * D) / 256;                 // 25000
static constexpr int PB_ZERO = ((int)ZERO_END + 255) / 256;
static constexpr int PB_WCVT = (L * 32768) / 256;             // 512
static constexpr int PB_FOLD = L;                             // 4
static constexpr int PB_TOTAL = PB_EMB + PB_ZERO + PB_WCVT + PB_FOLD;

// fused: embed (fp16) | zero | wcvt (fragment-ordered weights) | fold (edge proj fold, fp16)
__global__ __launch_bounds__(256) void prep_kernel(
        const int* __restrict__ xn, const float* __restrict__ emb, __half* __restrict__ xh,
        float* __restrict__ zbase,
        const float* __restrict__ Wl, const float* __restrict__ Wr, _Float16* __restrict__ wfrag,
        const float* __restrict__ edge_W, const float* __restrict__ edge_b,
        const float* __restrict__ We, _Float16* __restrict__ Mh, float* __restrict__ cfold) {
    int bid = blockIdx.x, t = threadIdx.x;
    if (bid < PB_EMB) {
        int i = bid * 256 + t;                     // N*D
        int n = i >> 7, c = i & 127;
        xh[i] = __float2half_rn(emb[xn[n] * D + c]);
    } else if (bid < PB_EMB + PB_ZERO) {
        int i = (bid - PB_EMB) * 256 + t;
        if (i < (int)ZERO_END) zbase[i] = 0.0f;
    } else if (bid < PB_EMB + PB_ZERO + PB_WCVT) {
        int i = (bid - PB_EMB - PB_ZERO) * 256 + t; // L*32768
        int j    = i & 7;
        int lane = (i >> 3) & 63;
        int nt   = (i >> 9) & 15;
        int kt   = (i >> 13) & 3;
        int l    = i >> 15;
        int k = kt * 32 + (lane >> 4) * 8 + j;
        int n = nt * 16 + (lane & 15);
        float v = (n < 128) ? Wl[((size_t)l * D + k) * D + n]
                            : Wr[((size_t)l * D + k) * D + (n - 128)];
        wfrag[i] = (_Float16)v;
    } else {
        int l = bid - PB_EMB - PB_ZERO - PB_WCVT;  // 4 blocks
        if (t >= 128) return;
        const float* Wel = We + (size_t)l * EE * D;
        for (int j = 0; j < EF; ++j) {
            float s = 0.f;
            for (int k = 0; k < EE; ++k) s += edge_W[j * EE + k] * Wel[k * D + t];
            Mh[((size_t)l * D + t) * 8 + j] = (_Float16)s;   // [l][c][j]
        }
        float s = 0.f;
        for (int k = 0; k < EE; ++k) s += edge_b[k] * Wel[k * D + t];
        cfold[l * D + t] = s;
    }
}

// pass 1: per-dst degree + per-edge slot (atomicAdd return), coalesced myoff write
__global__ void edge_cnt_kernel(const int* __restrict__ src, const int* __restrict__ dst,
                                int* __restrict__ cnt, int* __restrict__ myoff) {
    int e = blockIdx.x * blockDim.x + threadIdx.x;
    if (e >= E) return;
    int s = src[e], d = dst[e];
    myoff[e] = (s == d) ? -1 : atomicAdd(&cnt[d], 1);
}

__global__ void scan1_kernel(const int* __restrict__ cnt, int* __restrict__ out /*=csr_off+1*/,
                             int* __restrict__ bsum) {
    __shared__ int lds[256];
    int b = blockIdx.x, t = threadIdx.x;
    int base = b * 1024 + t * 4;
    int v[4]; int s = 0;
    #pragma unroll
    for (int k = 0; k < 4; ++k) { int idx = base + k; v[k] = (idx < N) ? cnt[idx] : 0; s += v[k]; }
    lds[t] = s; __syncthreads();
    for (int off = 1; off < 256; off <<= 1) {
        int add = (t >= off) ? lds[t - off] : 0;
        __syncthreads();
        lds[t] += add;
        __syncthreads();
    }
    int run = (t > 0) ? lds[t - 1] : 0;
    #pragma unroll
    for (int k = 0; k < 4; ++k) { run += v[k]; int idx = base + k; if (idx < N) out[idx] = run; }
    if (t == 255) bsum[b] = lds[255];
}

__global__ void scan3_kernel(int* __restrict__ csr_off, const int* __restrict__ bsum) {
    int i = blockIdx.x * blockDim.x + threadIdx.x;
    if (i == 0) csr_off[0] = 0;
    if (i >= N) return;
    int b = i >> 10;
    int add = 0;
    for (int k = 0; k < b; ++k) add += bsum[k];
    csr_off[1 + i] += add;
}

// pass 2: scattered write of 4B rank only (no atomics)
__global__ void rank_fill_kernel(const int* __restrict__ dst, const int* __restrict__ csr_off,
                                 const int* __restrict__ myoff, int* __restrict__ rank) {
    int e = blockIdx.x * blockDim.x + threadIdx.x;
    if (e >= E) return;
    int mo = myoff[e];
    if (mo < 0) return;
    rank[csr_off[dst[e]] + mo] = e;
}

// pass 3: coalesced heavy-stream build (random reads, sequential writes)
__global__ void csr_build_kernel(const int* __restrict__ rank, const int* __restrict__ src,
                                 const float* __restrict__ eattr, const int* __restrict__ total,
                                 int* __restrict__ csr_src, __half* __restrict__ csr_ea) {
    int pos = blockIdx.x * blockDim.x + threadIdx.x;
    if (pos >= *total) return;
    int e = rank[pos];
    csr_src[pos] = src[e] << 8;   // byte offset of row e's source (128 ch * 2 B)
    const float4* p = reinterpret_cast<const float4*>(eattr + (size_t)e * 8);
    float4 a = p[0], b = p[1];
    H4 h;
    h.h[0] = pkrtz(a.x, a.y); h.h[1] = pkrtz(a.z, a.w);
    h.h[2] = pkrtz(b.x, b.y); h.h[3] = pkrtz(b.z, b.w);
    *reinterpret_cast<f32x4*>(csr_ea + (size_t)pos * 8) = h.v4;
}

__global__ void loopmean_kernel(const int* __restrict__ csr_off, const __half* __restrict__ csr_ea,
                                __half* __restrict__ loopm, float* __restrict__ selff) {
    int i = blockIdx.x * blockDim.x + threadIdx.x;   // N*8
    int n = i >> 3, j = i & 7;
    if (n >= N) return;
    int beg = csr_off[n], end = csr_off[n + 1];
    float s = 0.f;
    for (int idx = beg; idx < end; ++idx) s += __half2float(csr_ea[(size_t)idx * 8 + j]);
    int c = end - beg;
    loopm[(size_t)n * 8 + j] = __float2half_rn(s / (float)(c > 1 ? c : 1));
    if (j == 0) selff[n] = (c > 0) ? 1.0f : 0.0f;
}

// [xl|xr] = x @ [Wl|Wr] + [bl|br] via f16 MFMA. Block=256 (4 waves), 16 nodes/block.
__global__ __launch_bounds__(256) void transform_kernel(
        const __half* __restrict__ xh, const _Float16* __restrict__ wfrag,
        const float* __restrict__ bl, const float* __restrict__ br,
        __half* __restrict__ xl_h, __half* __restrict__ xr_h) {
    int w = threadIdx.x >> 6, lane = threadIdx.x & 63;
    int quad = lane >> 4, r16 = lane & 15;
    int m0 = blockIdx.x * 16;
    const _Float16* xrow = reinterpret_cast<const _Float16*>(xh) + (size_t)(m0 + r16) * D + quad * 8;
    half8 a[4];
    #pragma unroll
    for (int kt = 0; kt < 4; ++kt) a[kt] = *reinterpret_cast<const half8*>(xrow + kt * 32);
    f32x4 acc[4];
    #pragma unroll
    for (int nt = 0; nt < 4; ++nt) { f32x4 z = {0.f, 0.f, 0.f, 0.f}; acc[nt] = z; }
    #pragma unroll
    for (int nt = 0; nt < 4; ++nt) {
        int ntile = w * 4 + nt;
        #pragma unroll
        for (int kt = 0; kt < 4; ++kt) {
            half8 b = *reinterpret_cast<const half8*>(
                wfrag + ((size_t)(kt * 16 + ntile) * 64 + lane) * 8);
            acc[nt] = __builtin_amdgcn_mfma_f32_16x16x32_f16(a[kt], b, acc[nt], 0, 0, 0);
        }
    }
    #pragma unroll
    for (int nt = 0; nt < 4; ++nt) {
        int n = (w * 4 + nt) * 16 + r16;
        float bias = (n < 128) ? bl[n] : br[n - 128];
        #pragma unroll
        for (int r = 0; r < 4; ++r) {
            int node = m0 + quad * 4 + r;
            float v = acc[nt][r] + bias;
            if (n < 128) xl_h[(size_t)node * D + n] = __float2half_rn(v);
            else         xr_h[(size_t)node * D + (n - 128)] = __float2half_rn(v);
        }
    }
}

// One wave per node (2 nodes / 128-block). Thread = 2 channels (packed fp16 math).
// Projection in f32 fdot2, z/leaky/logit in pk-f16, exp2 domain, fp16 packed acc, DPP reduce.
__global__ __launch_bounds__(128) void aggregate_kernel(
        const __half* __restrict__ xl_h, const __half* __restrict__ xr_h,
        const __half* __restrict__ loopm, const float* __restrict__ selff,
        const int* __restrict__ csr_off, const int* __restrict__ csr_src,
        const __half* __restrict__ csr_ea,
        const _Float16* __restrict__ Mh, const float* __restrict__ cfold,
        const float* __restrict__ att, const float* __restrict__ gbias,
        const float* __restrict__ bn_gamma, const float* __restrict__ bn_beta,
        __half* __restrict__ xout) {
    int n = blockIdx.x * 2 + (threadIdx.x >> 6);
    int t = threadIdx.x & 63;        // lane in wave
    int c0 = t * 2;                  // channels c0, c0+1; head = t>>3 (8 lanes/head)
    const char* xlb = reinterpret_cast<const char*>(xl_h);
    int lb = t << 2;                 // lane byte offset within a row (2 ch * 2 B)
    h2v attp = pkrtz(att[c0] * LOG2E, att[c0 + 1] * LOG2E);
    H4 m0u, m1u;
    m0u.f4 = *reinterpret_cast<const float4*>(Mh + (size_t)c0 * 8);
    m1u.f4 = *reinterpret_cast<const float4*>(Mh + (size_t)(c0 + 1) * 8);
    float cf0 = cfold[c0], cf1 = cfold[c0 + 1];
    h2v xrp = *reinterpret_cast<const h2v*>(xr_h + (size_t)n * D + c0);
    h2v xlp = *reinterpret_cast<const h2v*>(xl_h + (size_t)n * D + c0);
    const h2v c02 = {(_Float16)0.2f, (_Float16)0.2f};

    // self loop (edge attr = per-node mean of incoming raw attrs, fp16)
    H4 lau;
    lau.f4 = *reinterpret_cast<const float4*>(loopm + (size_t)n * 8);
    float sf = selff[n];
    float ep0 = cf0 * sf, ep1 = cf1 * sf;
    #pragma unroll
    for (int k = 0; k < 4; ++k) { ep0 = FDOT2(lau.h[k], m0u.h[k], ep0); ep1 = FDOT2(lau.h[k], m1u.h[k], ep1); }
    {
        f2v xlf = __builtin_convertvector(xlp, f2v);
        f2v xrf = __builtin_convertvector(xrp, f2v);
        float z0 = xlf[0] + xrf[0] + ep0; z0 = fmaxf(z0, 0.2f * z0);
        float z1 = xlf[1] + xrf[1] + ep1; z1 = fmaxf(z1, 0.2f * z1);
        ep0 = FDOT2(pkrtz(z0, z1), attp, 0.0f);
    }
    float m = red8(ep0);
    float denom = 1.0f;
    h2v acc = xlp;

    int beg = csr_off[n], end = csr_off[n + 1];
    for (int base = beg; base < end; base += 64) {
        int cnt = end - base; if (cnt > 64) cnt = 64;
        int sreg = (t < cnt) ? csr_src[base + t] : 0;   // coalesced; byte row offsets
        int i = 0;
        for (; i + 4 <= cnt; i += 4) {
            int o0 = __shfl(sreg, i),     o1 = __shfl(sreg, i + 1);
            int o2 = __shfl(sreg, i + 2), o3 = __shfl(sreg, i + 3);
            h2v g0 = *reinterpret_cast<const h2v*>(xlb + o0 + lb);
            h2v g1 = *reinterpret_cast<const h2v*>(xlb + o1 + lb);
            h2v g2 = *reinterpret_cast<const h2v*>(xlb + o2 + lb);
            h2v g3 = *reinterpret_cast<const h2v*>(xlb + o3 + lb);
            H4 e0u, e1u, e2u, e3u;
            e0u.f4 = *reinterpret_cast<const float4*>(csr_ea + (size_t)(base + i) * 8);
            e1u.f4 = *reinterpret_cast<const float4*>(csr_ea + (size_t)(base + i) * 8 + 8);
            e2u.f4 = *reinterpret_cast<const float4*>(csr_ea + (size_t)(base + i) * 8 + 16);
            e3u.f4 = *reinterpret_cast<const float4*>(csr_ea + (size_t)(base + i) * 8 + 24);
            float p00 = cf0, p01 = cf1, p10 = cf0, p11 = cf1;
            float p20 = cf0, p21 = cf1, p30 = cf0, p31 = cf1;
            #pragma unroll
            for (int k = 0; k < 4; ++k) {
                p00 = FDOT2(e0u.h[k], m0u.h[k], p00); p01 = FDOT2(e0u.h[k], m1u.h[k], p01);
                p10 = FDOT2(e1u.h[k], m0u.h[k], p10); p11 = FDOT2(e1u.h[k], m1u.h[k], p11);
                p20 = FDOT2(e2u.h[k], m0u.h[k], p20); p21 = FDOT2(e2u.h[k], m1u.h[k], p21);
                p30 = FDOT2(e3u.h[k], m0u.h[k], p30); p31 = FDOT2(e3u.h[k], m1u.h[k], p31);
            }
            h2v z0 = g0 + xrp + pkrtz(p00, p01);
            h2v z1 = g1 + xrp + pkrtz(p10, p11);
            h2v z2 = g2 + xrp + pkrtz(p20, p21);
            h2v z3 = g3 + xrp + pkrtz(p30, p31);
            z0 = hmax2(z0, z0 * c02); z1 = hmax2(z1, z1 * c02);
            z2 = hmax2(z2, z2 * c02); z3 = hmax2(z3, z3 * c02);
            float l0 = red8(FDOT2(z0, attp, 0.0f));
            float l1 = red8(FDOT2(z1, attp, 0.0f));
            float l2 = red8(FDOT2(z2, attp, 0.0f));
            float l3 = red8(FDOT2(z3, attp, 0.0f));
            float gm = fmaxf(fmaxf(l0, l1), fmaxf(l2, l3));
            float nm = fmaxf(m, gm);
            float wo = __builtin_amdgcn_exp2f(m - nm);
            float w0 = __builtin_amdgcn_exp2f(l0 - nm);
            float w1 = __builtin_amdgcn_exp2f(l1 - nm);
            float w2 = __builtin_amdgcn_exp2f(l2 - nm);
            float w3 = __builtin_amdgcn_exp2f(l3 - nm);
            denom = denom * wo + (w0 + w1) + (w2 + w3);
            acc = acc * pkrtz(wo, wo);
            acc = hfma2(pkrtz(w0, w0), g0, acc);
            acc = hfma2(pkrtz(w1, w1), g1, acc);
            acc = hfma2(pkrtz(w2, w2), g2, acc);
            acc = hfma2(pkrtz(w3, w3), g3, acc);
            m = nm;
        }
        for (; i < cnt; ++i) {
            int o0 = __shfl(sreg, i);
            h2v g0 = *reinterpret_cast<const h2v*>(xlb + o0 + lb);
            H4 e0u;
            e0u.f4 = *reinterpret_cast<const float4*>(csr_ea + (size_t)(base + i) * 8);
            float p00 = cf0, p01 = cf1;
            #pragma unroll
            for (int k = 0; k < 4; ++k) { p00 = FDOT2(e0u.h[k], m0u.h[k], p00); p01 = FDOT2(e0u.h[k], m1u.h[k], p01); }
            h2v z0 = g0 + xrp + pkrtz(p00, p01);
            z0 = hmax2(z0, z0 * c02);
            float l0 = red8(FDOT2(z0, attp, 0.0f));
            float nm = fmaxf(m, l0);
            float wo = __builtin_amdgcn_exp2f(m - nm);
            float w0 = __builtin_amdgcn_exp2f(l0 - nm);
            denom = denom * wo + w0;
            acc = acc * pkrtz(wo, wo);
            acc = hfma2(pkrtz(w0, w0), g0, acc);
            m = nm;
        }
    }
    f2v accf = __builtin_convertvector(acc, f2v);
    float inv = 1.0f / denom;
    float h0 = accf[0] * inv + gbias[c0];
    float h1 = accf[1] * inv + gbias[c0 + 1];
    h0 = bn_gamma[c0] * h0 * 0.999995000037499813f + bn_beta[c0];
    h1 = bn_gamma[c0 + 1] * h1 * 0.999995000037499813f + bn_beta[c0 + 1];
    h0 = h0 > 0.f ? h0 : (__expf(h0) - 1.0f);
    h1 = h1 > 0.f ? h1 : (__expf(h1) - 1.0f);
    *reinterpret_cast<__half2*>(xout + (size_t)n * D + c0) = __floats2half2_rn(h0, h1);
}

__device__ __forceinline__ int lower_bound_dev(const int* a, int n, int v) {
    int lo = 0, hi = n;
    while (lo < hi) { int mid = (lo + hi) >> 1; if (a[mid] < v) lo = mid + 1; else hi = mid; }
    return lo;
}

__global__ __launch_bounds__(128) void headpool_kernel(
        const __half* __restrict__ xh, const int* __restrict__ batch,
        const float* __restrict__ hW, const float* __restrict__ hb,
        float* __restrict__ out) {
    __shared__ float lds[128];
    int g = blockIdx.x, t = threadIdx.x;
    int lo = lower_bound_dev(batch, N, g);
    int hi = lower_bound_dev(batch, N, g + 1);
    float s = 0.f;
    #pragma unroll 4
    for (int i = lo; i < hi; ++i) s += __half2float(xh[(size_t)i * D + t]);
    int c = hi - lo;
    lds[t] = s / (float)(c > 1 ? c : 1);
    __syncthreads();
    if (t < NC) {
        float p = hb[t];
        #pragma unroll 8
        for (int cc = 0; cc < D; ++cc) p += lds[cc] * hW[cc * NC + t];
        out[g * NC + t] = p;
    }
}

extern "C" void kernel_launch(void* const* d_in, const int* in_sizes, int n_in,
                              void* d_out, int out_size, void* d_ws, size_t ws_size,
                              hipStream_t stream) {
    const int*   x_nodes   = (const int*)  d_in[0];
    const int*   edge_src  = (const int*)  d_in[1];
    const int*   edge_dst  = (const int*)  d_in[2];
    const float* edge_attr = (const float*)d_in[3];
    const int*   batch     = (const int*)  d_in[4];
    const float* node_emb  = (const float*)d_in[5];
    const float* edge_W    = (const float*)d_in[6];
    const float* edge_b    = (const float*)d_in[7];
    const float* Wl        = (const float*)d_in[8];
    const float* bl        = (const float*)d_in[9];
    const float* Wr        = (const float*)d_in[10];
    const float* br        = (const float*)d_in[11];
    const float* We        = (const float*)d_in[12];
    const float* att       = (const float*)d_in[13];
    const float* gbias     = (const float*)d_in[14];
    const float* bn_gamma  = (const float*)d_in[15];
    const float* bn_beta   = (const float*)d_in[16];
    const float* head_W    = (const float*)d_in[17];
    const float* head_b    = (const float*)d_in[18];
    float* out = (float*)d_out;

    float* ws = (float*)d_ws;
    int*    cnt      = (int*)(ws + O_CNT);
    int*    csr_off  = (int*)(ws + O_CSROFF);
    int*    bsum     = (int*)(ws + O_BSUM);
    int*    myoff    = (int*)(ws + O_MYOFF);
    int*    rank     = (int*)(ws + O_RANK);
    int*    csr_src  = (int*)(ws + O_CSRSRC);
    __half* csr_ea   = (__half*)(ws + O_CSREA);
    _Float16* Mh     = (_Float16*)(ws + O_MH);
    float*  cfold    = ws + O_CFOLD;
    __half* loopm    = (__half*)(ws + O_LOOPM);
    float*  selff    = ws + O_SELFF;
    _Float16* wfrag  = (_Float16*)(ws + O_WFRAG);
    __half* xh   = (__half*)(ws + O_XH);
    __half* xl_h = (__half*)(ws + O_XLH);
    __half* xr_h = (__half*)(ws + O_XRH);

    prep_kernel<<<PB_TOTAL, 256, 0, stream>>>(x_nodes, node_emb, xh, ws,
                                              Wl, Wr, wfrag, edge_W, edge_b, We, Mh, cfold);
    edge_cnt_kernel<<<(E + 255) / 256, 256, 0, stream>>>(edge_src, edge_dst, cnt, myoff);
    {
        int nb = (N + 1023) / 1024;   // 49
        scan1_kernel<<<nb, 256, 0, stream>>>(cnt, csr_off + 1, bsum);
        scan3_kernel<<<(N + 255) / 256, 256, 0, stream>>>(csr_off, bsum);
    }
    rank_fill_kernel<<<(E + 255) / 256, 256, 0, stream>>>(edge_dst, csr_off, myoff, rank);
    csr_build_kernel<<<(E + 255) / 256, 256, 0, stream>>>(rank, edge_src, edge_attr,
                                                          csr_off + N, csr_src, csr_ea);
    loopmean_kernel<<<(N * 8 + 255) / 256, 256, 0, stream>>>(csr_off, csr_ea, loopm, selff);
    for (int l = 0; l < L; ++l) {
        transform_kernel<<<N / 16, 256, 0, stream>>>(
            xh, wfrag + (size_t)l * 32768, bl + l * D, br + l * D, xl_h, xr_h);
        aggregate_kernel<<<N / 2, 128, 0, stream>>>(
            xl_h, xr_h, loopm, selff, csr_off, csr_src, csr_ea,
            Mh + (size_t)l * D * 8, cfold + l * D, att + l * D, gbias + l * D,
            bn_gamma + l * D, bn_beta + l * D, xh);
    }
    headpool_kernel<<<G, 128, 0, stream>>>(xh, batch, head_W, head_b, out);

    (void)in_sizes; (void)n_in; (void)out_size; (void)ws_size;
}

// Round 11
// 515.284 us; speedup vs baseline: 1.1017x; 1.0443x over previous
//
#include <hip/hip_runtime.h>
#include <hip/hip_fp16.h>
#include <math.h>

static constexpr int N  = 50000;
static constexpr int E  = 800000;
static constexpr int G  = 512;
static constexpr int D  = 128;
static constexpr int EF = 8;
static constexpr int EE = 64;
static constexpr int L  = 4;
static constexpr int NC = 10;

typedef _Float16 half8 __attribute__((ext_vector_type(8)));
typedef _Float16 h2v  __attribute__((ext_vector_type(2)));
typedef float f2v __attribute__((ext_vector_type(2)));
typedef float f32x4 __attribute__((ext_vector_type(4)));

union H4 { float4 f4; f32x4 v4; h2v h[4]; };

#if __has_builtin(__builtin_amdgcn_fdot2)
#define FDOT2(a, b, c) __builtin_amdgcn_fdot2((a), (b), (c), false)
#else
#define FDOT2(a, b, c) ((float)(a)[0]*(float)(b)[0] + (float)(a)[1]*(float)(b)[1] + (c))
#endif

__device__ __forceinline__ h2v pkrtz(float a, float b) {
    return (h2v)__builtin_amdgcn_cvt_pkrtz(a, b);
}
__device__ __forceinline__ h2v hmax2(h2v a, h2v b) {
#if __has_builtin(__builtin_elementwise_max)
    return __builtin_elementwise_max(a, b);
#else
    h2v r; r[0] = a[0] > b[0] ? a[0] : b[0]; r[1] = a[1] > b[1] ? a[1] : b[1]; return r;
#endif
}
__device__ __forceinline__ h2v hfma2(h2v a, h2v b, h2v c) {
#if __has_builtin(__builtin_elementwise_fma)
    return __builtin_elementwise_fma(a, b, c);
#else
    return a * b + c;
#endif
}
// sum over 8-lane head group (lanes t, t^1, t^2, t^4) via DPP — no LDS traffic
__device__ __forceinline__ float red8(float v) {
#if __has_builtin(__builtin_amdgcn_update_dpp)
    v += __builtin_bit_cast(float, __builtin_amdgcn_update_dpp(
            0, __builtin_bit_cast(int, v), 0xB1, 0xF, 0xF, true));   // quad_perm xor1
    v += __builtin_bit_cast(float, __builtin_amdgcn_update_dpp(
            0, __builtin_bit_cast(int, v), 0x4E, 0xF, 0xF, true));   // quad_perm xor2
    v += __builtin_bit_cast(float, __builtin_amdgcn_update_dpp(
            0, __builtin_bit_cast(int, v), 0x141, 0xF, 0xF, true));  // row_half_mirror
#else
    v += __shfl_xor(v, 1); v += __shfl_xor(v, 2); v += __shfl_xor(v, 4);
#endif
    return v;
}

#define LOG2E 1.44269504088896340736f

static constexpr size_t pad64(size_t w){ return (w + 63) & ~size_t(63); }
// workspace layout in 4-byte words; [0, ZERO_END) is zero-initialized by prep
static constexpr size_t O_CNT     = 0;                               // N ints
static constexpr size_t ZERO_END  = pad64(N);
static constexpr size_t O_CSROFF  = ZERO_END;                        // N+1 ints
static constexpr size_t O_BSUM    = O_CSROFF + pad64(N+1);           // 64 ints
static constexpr size_t O_MYOFF   = O_BSUM + 64;                     // E ints
static constexpr size_t O_RANK    = O_MYOFF + pad64(E);              // E ints
static constexpr size_t O_CSRSRC  = O_RANK + pad64(E);               // E ints (row BYTE offsets)
static constexpr size_t O_CSREA   = O_CSRSRC + pad64(E);             // E*8 halfs = E*4 words
static constexpr size_t O_MH      = O_CSREA + pad64((size_t)E*4);    // L*D*8 halfs
static constexpr size_t O_CFOLD   = O_MH + pad64((size_t)L*512);     // L*D f32
static constexpr size_t O_LOOPM   = O_CFOLD + pad64(L*D);            // N*8 halfs
static constexpr size_t O_SELFF   = O_LOOPM + pad64((size_t)N*4);    // N f32
static constexpr size_t O_WFRAG   = O_SELFF + pad64(N);              // L*32768 halfs
static constexpr size_t O_XH      = O_WFRAG + pad64((size_t)L*16384);// N*D halfs
static constexpr size_t O_XLH     = O_XH  + pad64((size_t)N*64);
static constexpr size_t O_XRH     = O_XLH + pad64((size_t)N*64);

// prep grid partition (256-thread blocks)
static constexpr int PB_EMB  = (N * D) / 256;                 // 25000
static constexpr int PB_ZERO = ((int)ZERO_END + 255) / 256;
static constexpr int PB_WCVT = (L * 32768) / 256;             // 512
static constexpr int PB_FOLD = L;                             // 4
static constexpr int PB_TOTAL = PB_EMB + PB_ZERO + PB_WCVT + PB_FOLD;

// fused: embed (fp16) | zero | wcvt (fragment-ordered weights) | fold (edge proj fold, fp16)
__global__ __launch_bounds__(256) void prep_kernel(
        const int* __restrict__ xn, const float* __restrict__ emb, __half* __restrict__ xh,
        float* __restrict__ zbase,
        const float* __restrict__ Wl, const float* __restrict__ Wr, _Float16* __restrict__ wfrag,
        const float* __restrict__ edge_W, const float* __restrict__ edge_b,
        const float* __restrict__ We, _Float16* __restrict__ Mh, float* __restrict__ cfold) {
    int bid = blockIdx.x, t = threadIdx.x;
    if (bid < PB_EMB) {
        int i = bid * 256 + t;                     // N*D
        int n = i >> 7, c = i & 127;
        xh[i] = __float2half_rn(emb[xn[n] * D + c]);
    } else if (bid < PB_EMB + PB_ZERO) {
        int i = (bid - PB_EMB) * 256 + t;
        if (i < (int)ZERO_END) zbase[i] = 0.0f;
    } else if (bid < PB_EMB + PB_ZERO + PB_WCVT) {
        int i = (bid - PB_EMB - PB_ZERO) * 256 + t; // L*32768
        int j    = i & 7;
        int lane = (i >> 3) & 63;
        int nt   = (i >> 9) & 15;
        int kt   = (i >> 13) & 3;
        int l    = i >> 15;
        int k = kt * 32 + (lane >> 4) * 8 + j;
        int n = nt * 16 + (lane & 15);
        float v = (n < 128) ? Wl[((size_t)l * D + k) * D + n]
                            : Wr[((size_t)l * D + k) * D + (n - 128)];
        wfrag[i] = (_Float16)v;
    } else {
        int l = bid - PB_EMB - PB_ZERO - PB_WCVT;  // 4 blocks
        if (t >= 128) return;
        const float* Wel = We + (size_t)l * EE * D;
        for (int j = 0; j < EF; ++j) {
            float s = 0.f;
            for (int k = 0; k < EE; ++k) s += edge_W[j * EE + k] * Wel[k * D + t];
            Mh[((size_t)l * D + t) * 8 + j] = (_Float16)s;   // [l][c][j]
        }
        float s = 0.f;
        for (int k = 0; k < EE; ++k) s += edge_b[k] * Wel[k * D + t];
        cfold[l * D + t] = s;
    }
}

// pass 1: per-dst degree + per-edge slot (atomicAdd return), coalesced myoff write
__global__ void edge_cnt_kernel(const int* __restrict__ src, const int* __restrict__ dst,
                                int* __restrict__ cnt, int* __restrict__ myoff) {
    int e = blockIdx.x * blockDim.x + threadIdx.x;
    if (e >= E) return;
    int s = src[e], d = dst[e];
    myoff[e] = (s == d) ? -1 : atomicAdd(&cnt[d], 1);
}

__global__ void scan1_kernel(const int* __restrict__ cnt, int* __restrict__ out /*=csr_off+1*/,
                             int* __restrict__ bsum) {
    __shared__ int lds[256];
    int b = blockIdx.x, t = threadIdx.x;
    int base = b * 1024 + t * 4;
    int v[4]; int s = 0;
    #pragma unroll
    for (int k = 0; k < 4; ++k) { int idx = base + k; v[k] = (idx < N) ? cnt[idx] : 0; s += v[k]; }
    lds[t] = s; __syncthreads();
    for (int off = 1; off < 256; off <<= 1) {
        int add = (t >= off) ? lds[t - off] : 0;
        __syncthreads();
        lds[t] += add;
        __syncthreads();
    }
    int run = (t > 0) ? lds[t - 1] : 0;
    #pragma unroll
    for (int k = 0; k < 4; ++k) { run += v[k]; int idx = base + k; if (idx < N) out[idx] = run; }
    if (t == 255) bsum[b] = lds[255];
}

__global__ void scan3_kernel(int* __restrict__ csr_off, const int* __restrict__ bsum) {
    int i = blockIdx.x * blockDim.x + threadIdx.x;
    if (i == 0) csr_off[0] = 0;
    if (i >= N) return;
    int b = i >> 10;
    int add = 0;
    for (int k = 0; k < b; ++k) add += bsum[k];
    csr_off[1 + i] += add;
}

// pass 2: scattered write of 4B rank only (no atomics)
__global__ void rank_fill_kernel(const int* __restrict__ dst, const int* __restrict__ csr_off,
                                 const int* __restrict__ myoff, int* __restrict__ rank) {
    int e = blockIdx.x * blockDim.x + threadIdx.x;
    if (e >= E) return;
    int mo = myoff[e];
    if (mo < 0) return;
    rank[csr_off[dst[e]] + mo] = e;
}

// pass 3: coalesced heavy-stream build (random reads, sequential writes)
__global__ void csr_build_kernel(const int* __restrict__ rank, const int* __restrict__ src,
                                 const float* __restrict__ eattr, const int* __restrict__ total,
                                 int* __restrict__ csr_src, __half* __restrict__ csr_ea) {
    int pos = blockIdx.x * blockDim.x + threadIdx.x;
    if (pos >= *total) return;
    int e = rank[pos];
    csr_src[pos] = src[e] << 8;   // byte offset of row e's source (128 ch * 2 B)
    const float4* p = reinterpret_cast<const float4*>(eattr + (size_t)e * 8);
    float4 a = p[0], b = p[1];
    H4 h;
    h.h[0] = pkrtz(a.x, a.y); h.h[1] = pkrtz(a.z, a.w);
    h.h[2] = pkrtz(b.x, b.y); h.h[3] = pkrtz(b.z, b.w);
    *reinterpret_cast<f32x4*>(csr_ea + (size_t)pos * 8) = h.v4;
}

__global__ void loopmean_kernel(const int* __restrict__ csr_off, const __half* __restrict__ csr_ea,
                                __half* __restrict__ loopm, float* __restrict__ selff) {
    int i = blockIdx.x * blockDim.x + threadIdx.x;   // N*8
    int n = i >> 3, j = i & 7;
    if (n >= N) return;
    int beg = csr_off[n], end = csr_off[n + 1];
    float s = 0.f;
    for (int idx = beg; idx < end; ++idx) s += __half2float(csr_ea[(size_t)idx * 8 + j]);
    int c = end - beg;
    loopm[(size_t)n * 8 + j] = __float2half_rn(s / (float)(c > 1 ? c : 1));
    if (j == 0) selff[n] = (c > 0) ? 1.0f : 0.0f;
}

// [xl|xr] = x @ [Wl|Wr] + [bl|br] via f16 MFMA. Block=256 (4 waves), 16 nodes/block.
__global__ __launch_bounds__(256) void transform_kernel(
        const __half* __restrict__ xh, const _Float16* __restrict__ wfrag,
        const float* __restrict__ bl, const float* __restrict__ br,
        __half* __restrict__ xl_h, __half* __restrict__ xr_h) {
    int w = threadIdx.x >> 6, lane = threadIdx.x & 63;
    int quad = lane >> 4, r16 = lane & 15;
    int m0 = blockIdx.x * 16;
    const _Float16* xrow = reinterpret_cast<const _Float16*>(xh) + (size_t)(m0 + r16) * D + quad * 8;
    half8 a[4];
    #pragma unroll
    for (int kt = 0; kt < 4; ++kt) a[kt] = *reinterpret_cast<const half8*>(xrow + kt * 32);
    f32x4 acc[4];
    #pragma unroll
    for (int nt = 0; nt < 4; ++nt) { f32x4 z = {0.f, 0.f, 0.f, 0.f}; acc[nt] = z; }
    #pragma unroll
    for (int nt = 0; nt < 4; ++nt) {
        int ntile = w * 4 + nt;
        #pragma unroll
        for (int kt = 0; kt < 4; ++kt) {
            half8 b = *reinterpret_cast<const half8*>(
                wfrag + ((size_t)(kt * 16 + ntile) * 64 + lane) * 8);
            acc[nt] = __builtin_amdgcn_mfma_f32_16x16x32_f16(a[kt], b, acc[nt], 0, 0, 0);
        }
    }
    #pragma unroll
    for (int nt = 0; nt < 4; ++nt) {
        int n = (w * 4 + nt) * 16 + r16;
        float bias = (n < 128) ? bl[n] : br[n - 128];
        #pragma unroll
        for (int r = 0; r < 4; ++r) {
            int node = m0 + quad * 4 + r;
            float v = acc[nt][r] + bias;
            if (n < 128) xl_h[(size_t)node * D + n] = __float2half_rn(v);
            else         xr_h[(size_t)node * D + (n - 128)] = __float2half_rn(v);
        }
    }
}

// One wave per node (64-thread block). Thread = 2 channels (packed fp16 math).
// Projection in f32 fdot2, z/leaky/logit in pk-f16, exp2 domain, fp16 packed acc, DPP reduce.
__global__ __launch_bounds__(64) void aggregate_kernel(
        const __half* __restrict__ xl_h, const __half* __restrict__ xr_h,
        const __half* __restrict__ loopm, const float* __restrict__ selff,
        const int* __restrict__ csr_off, const int* __restrict__ csr_src,
        const __half* __restrict__ csr_ea,
        const _Float16* __restrict__ Mh, const float* __restrict__ cfold,
        const float* __restrict__ att, const float* __restrict__ gbias,
        const float* __restrict__ bn_gamma, const float* __restrict__ bn_beta,
        __half* __restrict__ xout) {
    int n = blockIdx.x;
    int t = threadIdx.x;             // lane in wave
    int c0 = t * 2;                  // channels c0, c0+1; head = t>>3 (8 lanes/head)
    const char* xlb = reinterpret_cast<const char*>(xl_h);
    int lb = t << 2;                 // lane byte offset within a row (2 ch * 2 B)
    h2v attp = pkrtz(att[c0] * LOG2E, att[c0 + 1] * LOG2E);
    H4 m0u, m1u;
    m0u.f4 = *reinterpret_cast<const float4*>(Mh + (size_t)c0 * 8);
    m1u.f4 = *reinterpret_cast<const float4*>(Mh + (size_t)(c0 + 1) * 8);
    float cf0 = cfold[c0], cf1 = cfold[c0 + 1];
    h2v xrp = *reinterpret_cast<const h2v*>(xr_h + (size_t)n * D + c0);
    h2v xlp = *reinterpret_cast<const h2v*>(xl_h + (size_t)n * D + c0);
    const h2v c02 = {(_Float16)0.2f, (_Float16)0.2f};

    // self loop (edge attr = per-node mean of incoming raw attrs, fp16)
    H4 lau;
    lau.f4 = *reinterpret_cast<const float4*>(loopm + (size_t)n * 8);
    float sf = selff[n];
    float ep0 = cf0 * sf, ep1 = cf1 * sf;
    #pragma unroll
    for (int k = 0; k < 4; ++k) { ep0 = FDOT2(lau.h[k], m0u.h[k], ep0); ep1 = FDOT2(lau.h[k], m1u.h[k], ep1); }
    {
        f2v xlf = __builtin_convertvector(xlp, f2v);
        f2v xrf = __builtin_convertvector(xrp, f2v);
        float z0 = xlf[0] + xrf[0] + ep0; z0 = fmaxf(z0, 0.2f * z0);
        float z1 = xlf[1] + xrf[1] + ep1; z1 = fmaxf(z1, 0.2f * z1);
        ep0 = FDOT2(pkrtz(z0, z1), attp, 0.0f);
    }
    float m = red8(ep0);
    float denom = 1.0f;
    h2v acc = xlp;

    int beg = csr_off[n], end = csr_off[n + 1];
    for (int base = beg; base < end; base += 64) {
        int cnt = end - base; if (cnt > 64) cnt = 64;
        int sreg = (t < cnt) ? csr_src[base + t] : 0;   // coalesced; byte row offsets
        int i = 0;
        for (; i + 4 <= cnt; i += 4) {
            int o0 = __shfl(sreg, i),     o1 = __shfl(sreg, i + 1);
            int o2 = __shfl(sreg, i + 2), o3 = __shfl(sreg, i + 3);
            h2v g0 = *reinterpret_cast<const h2v*>(xlb + o0 + lb);
            h2v g1 = *reinterpret_cast<const h2v*>(xlb + o1 + lb);
            h2v g2 = *reinterpret_cast<const h2v*>(xlb + o2 + lb);
            h2v g3 = *reinterpret_cast<const h2v*>(xlb + o3 + lb);
            H4 e0u, e1u, e2u, e3u;
            e0u.f4 = *reinterpret_cast<const float4*>(csr_ea + (size_t)(base + i) * 8);
            e1u.f4 = *reinterpret_cast<const float4*>(csr_ea + (size_t)(base + i) * 8 + 8);
            e2u.f4 = *reinterpret_cast<const float4*>(csr_ea + (size_t)(base + i) * 8 + 16);
            e3u.f4 = *reinterpret_cast<const float4*>(csr_ea + (size_t)(base + i) * 8 + 24);
            float p00 = cf0, p01 = cf1, p10 = cf0, p11 = cf1;
            float p20 = cf0, p21 = cf1, p30 = cf0, p31 = cf1;
            #pragma unroll
            for (int k = 0; k < 4; ++k) {
                p00 = FDOT2(e0u.h[k], m0u.h[k], p00); p01 = FDOT2(e0u.h[k], m1u.h[k], p01);
                p10 = FDOT2(e1u.h[k], m0u.h[k], p10); p11 = FDOT2(e1u.h[k], m1u.h[k], p11);
                p20 = FDOT2(e2u.h[k], m0u.h[k], p20); p21 = FDOT2(e2u.h[k], m1u.h[k], p21);
                p30 = FDOT2(e3u.h[k], m0u.h[k], p30); p31 = FDOT2(e3u.h[k], m1u.h[k], p31);
            }
            h2v z0 = g0 + xrp + pkrtz(p00, p01);
            h2v z1 = g1 + xrp + pkrtz(p10, p11);
            h2v z2 = g2 + xrp + pkrtz(p20, p21);
            h2v z3 = g3 + xrp + pkrtz(p30, p31);
            z0 = hmax2(z0, z0 * c02); z1 = hmax2(z1, z1 * c02);
            z2 = hmax2(z2, z2 * c02); z3 = hmax2(z3, z3 * c02);
            float l0 = red8(FDOT2(z0, attp, 0.0f));
            float l1 = red8(FDOT2(z1, attp, 0.0f));
            float l2 = red8(FDOT2(z2, attp, 0.0f));
            float l3 = red8(FDOT2(z3, attp, 0.0f));
            float gm = fmaxf(fmaxf(l0, l1), fmaxf(l2, l3));
            float nm = fmaxf(m, gm);
            float wo = __builtin_amdgcn_exp2f(m - nm);
            float w0 = __builtin_amdgcn_exp2f(l0 - nm);
            float w1 = __builtin_amdgcn_exp2f(l1 - nm);
            float w2 = __builtin_amdgcn_exp2f(l2 - nm);
            float w3 = __builtin_amdgcn_exp2f(l3 - nm);
            denom = denom * wo + (w0 + w1) + (w2 + w3);
            acc = acc * pkrtz(wo, wo);
            acc = hfma2(pkrtz(w0, w0), g0, acc);
            acc = hfma2(pkrtz(w1, w1), g1, acc);
            acc = hfma2(pkrtz(w2, w2), g2, acc);
            acc = hfma2(pkrtz(w3, w3), g3, acc);
            m = nm;
        }
        for (; i < cnt; ++i) {
            int o0 = __shfl(sreg, i);
            h2v g0 = *reinterpret_cast<const h2v*>(xlb + o0 + lb);
            H4 e0u;
            e0u.f4 = *reinterpret_cast<const float4*>(csr_ea + (size_t)(base + i) * 8);
            float p00 = cf0, p01 = cf1;
            #pragma unroll
            for (int k = 0; k < 4; ++k) { p00 = FDOT2(e0u.h[k], m0u.h[k], p00); p01 = FDOT2(e0u.h[k], m1u.h[k], p01); }
            h2v z0 = g0 + xrp + pkrtz(p00, p01);
            z0 = hmax2(z0, z0 * c02);
            float l0 = red8(FDOT2(z0, attp, 0.0f));
            float nm = fmaxf(m, l0);
            float wo = __builtin_amdgcn_exp2f(m - nm);
            float w0 = __builtin_amdgcn_exp2f(l0 - nm);
            denom = denom * wo + w0;
            acc = acc * pkrtz(wo, wo);
            acc = hfma2(pkrtz(w0, w0), g0, acc);
            m = nm;
        }
    }
    f2v accf = __builtin_convertvector(acc, f2v);
    float inv = 1.0f / denom;
    float h0 = accf[0] * inv + gbias[c0];
    float h1 = accf[1] * inv + gbias[c0 + 1];
    h0 = bn_gamma[c0] * h0 * 0.999995000037499813f + bn_beta[c0];
    h1 = bn_gamma[c0 + 1] * h1 * 0.999995000037499813f + bn_beta[c0 + 1];
    h0 = h0 > 0.f ? h0 : (__expf(h0) - 1.0f);
    h1 = h1 > 0.f ? h1 : (__expf(h1) - 1.0f);
    *reinterpret_cast<__half2*>(xout + (size_t)n * D + c0) = __floats2half2_rn(h0, h1);
}

__device__ __forceinline__ int lower_bound_dev(const int* a, int n, int v) {
    int lo = 0, hi = n;
    while (lo < hi) { int mid = (lo + hi) >> 1; if (a[mid] < v) lo = mid + 1; else hi = mid; }
    return lo;
}

__global__ __launch_bounds__(128) void headpool_kernel(
        const __half* __restrict__ xh, const int* __restrict__ batch,
        const float* __restrict__ hW, const float* __restrict__ hb,
        float* __restrict__ out) {
    __shared__ float lds[128];
    int g = blockIdx.x, t = threadIdx.x;
    int lo = lower_bound_dev(batch, N, g);
    int hi = lower_bound_dev(batch, N, g + 1);
    float s = 0.f;
    #pragma unroll 4
    for (int i = lo; i < hi; ++i) s += __half2float(xh[(size_t)i * D + t]);
    int c = hi - lo;
    lds[t] = s / (float)(c > 1 ? c : 1);
    __syncthreads();
    if (t < NC) {
        float p = hb[t];
        #pragma unroll 8
        for (int cc = 0; cc < D; ++cc) p += lds[cc] * hW[cc * NC + t];
        out[g * NC + t] = p;
    }
}

extern "C" void kernel_launch(void* const* d_in, const int* in_sizes, int n_in,
                              void* d_out, int out_size, void* d_ws, size_t ws_size,
                              hipStream_t stream) {
    const int*   x_nodes   = (const int*)  d_in[0];
    const int*   edge_src  = (const int*)  d_in[1];
    const int*   edge_dst  = (const int*)  d_in[2];
    const float* edge_attr = (const float*)d_in[3];
    const int*   batch     = (const int*)  d_in[4];
    const float* node_emb  = (const float*)d_in[5];
    const float* edge_W    = (const float*)d_in[6];
    const float* edge_b    = (const float*)d_in[7];
    const float* Wl        = (const float*)d_in[8];
    const float* bl        = (const float*)d_in[9];
    const float* Wr        = (const float*)d_in[10];
    const float* br        = (const float*)d_in[11];
    const float* We        = (const float*)d_in[12];
    const float* att       = (const float*)d_in[13];
    const float* gbias     = (const float*)d_in[14];
    const float* bn_gamma  = (const float*)d_in[15];
    const float* bn_beta   = (const float*)d_in[16];
    const float* head_W    = (const float*)d_in[17];
    const float* head_b    = (const float*)d_in[18];
    float* out = (float*)d_out;

    float* ws = (float*)d_ws;
    int*    cnt      = (int*)(ws + O_CNT);
    int*    csr_off  = (int*)(ws + O_CSROFF);
    int*    bsum     = (int*)(ws + O_BSUM);
    int*    myoff    = (int*)(ws + O_MYOFF);
    int*    rank     = (int*)(ws + O_RANK);
    int*    csr_src  = (int*)(ws + O_CSRSRC);
    __half* csr_ea   = (__half*)(ws + O_CSREA);
    _Float16* Mh     = (_Float16*)(ws + O_MH);
    float*  cfold    = ws + O_CFOLD;
    __half* loopm    = (__half*)(ws + O_LOOPM);
    float*  selff    = ws + O_SELFF;
    _Float16* wfrag  = (_Float16*)(ws + O_WFRAG);
    __half* xh   = (__half*)(ws + O_XH);
    __half* xl_h = (__half*)(ws + O_XLH);
    __half* xr_h = (__half*)(ws + O_XRH);

    prep_kernel<<<PB_TOTAL, 256, 0, stream>>>(x_nodes, node_emb, xh, ws,
                                              Wl, Wr, wfrag, edge_W, edge_b, We, Mh, cfold);
    edge_cnt_kernel<<<(E + 255) / 256, 256, 0, stream>>>(edge_src, edge_dst, cnt, myoff);
    {
        int nb = (N + 1023) / 1024;   // 49
        scan1_kernel<<<nb, 256, 0, stream>>>(cnt, csr_off + 1, bsum);
        scan3_kernel<<<(N + 255) / 256, 256, 0, stream>>>(csr_off, bsum);
    }
    rank_fill_kernel<<<(E + 255) / 256, 256, 0, stream>>>(edge_dst, csr_off, myoff, rank);
    csr_build_kernel<<<(E + 255) / 256, 256, 0, stream>>>(rank, edge_src, edge_attr,
                                                          csr_off + N, csr_src, csr_ea);
    loopmean_kernel<<<(N * 8 + 255) / 256, 256, 0, stream>>>(csr_off, csr_ea, loopm, selff);
    for (int l = 0; l < L; ++l) {
        transform_kernel<<<N / 16, 256, 0, stream>>>(
            xh, wfrag + (size_t)l * 32768, bl + l * D, br + l * D, xl_h, xr_h);
        aggregate_kernel<<<N, 64, 0, stream>>>(
            xl_h, xr_h, loopm, selff, csr_off, csr_src, csr_ea,
            Mh + (size_t)l * D * 8, cfold + l * D, att + l * D, gbias + l * D,
            bn_gamma + l * D, bn_beta + l * D, xh);
    }
    headpool_kernel<<<G, 128, 0, stream>>>(xh, batch, head_W, head_b, out);

    (void)in_sizes; (void)n_in; (void)out_size; (void)ws_size;
}

// Round 12
// 513.852 us; speedup vs baseline: 1.1048x; 1.0028x over previous
//
#include <hip/hip_runtime.h>
#include <hip/hip_fp16.h>
#include <math.h>

static constexpr int N  = 50000;
static constexpr int E  = 800000;
static constexpr int G  = 512;
static constexpr int D  = 128;
static constexpr int EF = 8;
static constexpr int EE = 64;
static constexpr int L  = 4;
static constexpr int NC = 10;

typedef _Float16 half8 __attribute__((ext_vector_type(8)));
typedef _Float16 h2v  __attribute__((ext_vector_type(2)));
typedef float f2v __attribute__((ext_vector_type(2)));
typedef float f32x4 __attribute__((ext_vector_type(4)));

union H4 { float4 f4; f32x4 v4; h2v h[4]; };

#if __has_builtin(__builtin_amdgcn_fdot2)
#define FDOT2(a, b, c) __builtin_amdgcn_fdot2((a), (b), (c), false)
#else
#define FDOT2(a, b, c) ((float)(a)[0]*(float)(b)[0] + (float)(a)[1]*(float)(b)[1] + (c))
#endif

__device__ __forceinline__ h2v pkrtz(float a, float b) {
    return (h2v)__builtin_amdgcn_cvt_pkrtz(a, b);
}
__device__ __forceinline__ h2v hmax2(h2v a, h2v b) {
#if __has_builtin(__builtin_elementwise_max)
    return __builtin_elementwise_max(a, b);
#else
    h2v r; r[0] = a[0] > b[0] ? a[0] : b[0]; r[1] = a[1] > b[1] ? a[1] : b[1]; return r;
#endif
}
__device__ __forceinline__ h2v hfma2(h2v a, h2v b, h2v c) {
#if __has_builtin(__builtin_elementwise_fma)
    return __builtin_elementwise_fma(a, b, c);
#else
    return a * b + c;
#endif
}
// sum over 8-lane head group (lanes t, t^1, t^2, t^4) via DPP — no LDS traffic
__device__ __forceinline__ float red8(float v) {
#if __has_builtin(__builtin_amdgcn_update_dpp)
    v += __builtin_bit_cast(float, __builtin_amdgcn_update_dpp(
            0, __builtin_bit_cast(int, v), 0xB1, 0xF, 0xF, true));   // quad_perm xor1
    v += __builtin_bit_cast(float, __builtin_amdgcn_update_dpp(
            0, __builtin_bit_cast(int, v), 0x4E, 0xF, 0xF, true));   // quad_perm xor2
    v += __builtin_bit_cast(float, __builtin_amdgcn_update_dpp(
            0, __builtin_bit_cast(int, v), 0x141, 0xF, 0xF, true));  // row_half_mirror
#else
    v += __shfl_xor(v, 1); v += __shfl_xor(v, 2); v += __shfl_xor(v, 4);
#endif
    return v;
}

#define LOG2E 1.44269504088896340736f

static constexpr size_t pad64(size_t w){ return (w + 63) & ~size_t(63); }
// workspace layout in 4-byte words; cnt is zeroed by hipMemsetAsync
static constexpr size_t O_CNT     = 0;                               // N ints
static constexpr size_t O_CSROFF  = pad64(N);                        // N+1 ints
static constexpr size_t O_BSUM    = O_CSROFF + pad64(N+1);           // 64 ints
static constexpr size_t O_MYOFF   = O_BSUM + 64;                     // E ints
static constexpr size_t O_RANK    = O_MYOFF + pad64(E);              // E ints
static constexpr size_t O_CSRSRC  = O_RANK + pad64(E);               // E ints (row BYTE offsets)
static constexpr size_t O_CSREA   = O_CSRSRC + pad64(E);             // E*8 halfs = E*4 words
static constexpr size_t O_MH      = O_CSREA + pad64((size_t)E*4);    // L*D*8 halfs
static constexpr size_t O_CFOLD   = O_MH + pad64((size_t)L*512);     // L*D f32
static constexpr size_t O_LOOPM   = O_CFOLD + pad64(L*D);            // N*8 halfs
static constexpr size_t O_SELFF   = O_LOOPM + pad64((size_t)N*4);    // N f32
static constexpr size_t O_WFRAG   = O_SELFF + pad64(N);              // L*32768 halfs
static constexpr size_t O_XH      = O_WFRAG + pad64((size_t)L*16384);// N*D halfs
static constexpr size_t O_XLH     = O_XH  + pad64((size_t)N*64);
static constexpr size_t O_XRH     = O_XLH + pad64((size_t)N*64);

// prep grid partition (256-thread blocks)
static constexpr int PB_EMB  = (N * D) / 256;                 // 25000
static constexpr int PB_ECNT = E / 256;                       // 3125
static constexpr int PB_WCVT = (L * 32768) / 256;             // 512
static constexpr int PB_FOLD = L;                             // 4
static constexpr int PB_TOTAL = PB_EMB + PB_ECNT + PB_WCVT + PB_FOLD;

// fused: embed (fp16) | edge-degree+slot | wcvt (fragment weights) | fold (edge proj, fp16)
__global__ __launch_bounds__(256) void prep_kernel(
        const int* __restrict__ xn, const float* __restrict__ emb, __half* __restrict__ xh,
        const int* __restrict__ esrc, const int* __restrict__ edst,
        int* __restrict__ cnt, int* __restrict__ myoff,
        const float* __restrict__ Wl, const float* __restrict__ Wr, _Float16* __restrict__ wfrag,
        const float* __restrict__ edge_W, const float* __restrict__ edge_b,
        const float* __restrict__ We, _Float16* __restrict__ Mh, float* __restrict__ cfold) {
    int bid = blockIdx.x, t = threadIdx.x;
    if (bid < PB_EMB) {
        int i = bid * 256 + t;                     // N*D
        int n = i >> 7, c = i & 127;
        xh[i] = __float2half_rn(emb[xn[n] * D + c]);
    } else if (bid < PB_EMB + PB_ECNT) {
        int e = (bid - PB_EMB) * 256 + t;          // one edge per thread
        int s = esrc[e], d = edst[e];
        myoff[e] = (s == d) ? -1 : atomicAdd(&cnt[d], 1);
    } else if (bid < PB_EMB + PB_ECNT + PB_WCVT) {
        int i = (bid - PB_EMB - PB_ECNT) * 256 + t; // L*32768
        int j    = i & 7;
        int lane = (i >> 3) & 63;
        int nt   = (i >> 9) & 15;
        int kt   = (i >> 13) & 3;
        int l    = i >> 15;
        int k = kt * 32 + (lane >> 4) * 8 + j;
        int n = nt * 16 + (lane & 15);
        float v = (n < 128) ? Wl[((size_t)l * D + k) * D + n]
                            : Wr[((size_t)l * D + k) * D + (n - 128)];
        wfrag[i] = (_Float16)v;
    } else {
        int l = bid - PB_EMB - PB_ECNT - PB_WCVT;  // 4 blocks
        if (t >= 128) return;
        const float* Wel = We + (size_t)l * EE * D;
        for (int j = 0; j < EF; ++j) {
            float s = 0.f;
            for (int k = 0; k < EE; ++k) s += edge_W[j * EE + k] * Wel[k * D + t];
            Mh[((size_t)l * D + t) * 8 + j] = (_Float16)s;   // [l][c][j]
        }
        float s = 0.f;
        for (int k = 0; k < EE; ++k) s += edge_b[k] * Wel[k * D + t];
        cfold[l * D + t] = s;
    }
}

__global__ void scan1_kernel(const int* __restrict__ cnt, int* __restrict__ out /*=csr_off+1*/,
                             int* __restrict__ bsum) {
    __shared__ int lds[256];
    int b = blockIdx.x, t = threadIdx.x;
    int base = b * 1024 + t * 4;
    int v[4]; int s = 0;
    #pragma unroll
    for (int k = 0; k < 4; ++k) { int idx = base + k; v[k] = (idx < N) ? cnt[idx] : 0; s += v[k]; }
    lds[t] = s; __syncthreads();
    for (int off = 1; off < 256; off <<= 1) {
        int add = (t >= off) ? lds[t - off] : 0;
        __syncthreads();
        lds[t] += add;
        __syncthreads();
    }
    int run = (t > 0) ? lds[t - 1] : 0;
    #pragma unroll
    for (int k = 0; k < 4; ++k) { run += v[k]; int idx = base + k; if (idx < N) out[idx] = run; }
    if (t == 255) bsum[b] = lds[255];
}

__global__ void scan3_kernel(int* __restrict__ csr_off, const int* __restrict__ bsum) {
    int i = blockIdx.x * blockDim.x + threadIdx.x;
    if (i == 0) csr_off[0] = 0;
    if (i >= N) return;
    int b = i >> 10;
    int add = 0;
    for (int k = 0; k < b; ++k) add += bsum[k];
    csr_off[1 + i] += add;
}

// scattered write of 4B rank only (no atomics)
__global__ void rank_fill_kernel(const int* __restrict__ dst, const int* __restrict__ csr_off,
                                 const int* __restrict__ myoff, int* __restrict__ rank) {
    int e = blockIdx.x * blockDim.x + threadIdx.x;
    if (e >= E) return;
    int mo = myoff[e];
    if (mo < 0) return;
    rank[csr_off[dst[e]] + mo] = e;
}

// coalesced heavy-stream build (random reads, sequential writes)
__global__ void csr_build_kernel(const int* __restrict__ rank, const int* __restrict__ src,
                                 const float* __restrict__ eattr, const int* __restrict__ total,
                                 int* __restrict__ csr_src, __half* __restrict__ csr_ea) {
    int pos = blockIdx.x * blockDim.x + threadIdx.x;
    if (pos >= *total) return;
    int e = rank[pos];
    csr_src[pos] = src[e] << 8;   // byte offset of row e's source (128 ch * 2 B)
    const float4* p = reinterpret_cast<const float4*>(eattr + (size_t)e * 8);
    float4 a = p[0], b = p[1];
    H4 h;
    h.h[0] = pkrtz(a.x, a.y); h.h[1] = pkrtz(a.z, a.w);
    h.h[2] = pkrtz(b.x, b.y); h.h[3] = pkrtz(b.z, b.w);
    *reinterpret_cast<f32x4*>(csr_ea + (size_t)pos * 8) = h.v4;
}

__global__ void loopmean_kernel(const int* __restrict__ csr_off, const __half* __restrict__ csr_ea,
                                __half* __restrict__ loopm, float* __restrict__ selff) {
    int i = blockIdx.x * blockDim.x + threadIdx.x;   // N*8
    int n = i >> 3, j = i & 7;
    if (n >= N) return;
    int beg = csr_off[n], end = csr_off[n + 1];
    float s = 0.f;
    for (int idx = beg; idx < end; ++idx) s += __half2float(csr_ea[(size_t)idx * 8 + j]);
    int c = end - beg;
    loopm[(size_t)n * 8 + j] = __float2half_rn(s / (float)(c > 1 ? c : 1));
    if (j == 0) selff[n] = (c > 0) ? 1.0f : 0.0f;
}

// [xl|xr] = x @ [Wl|Wr] + [bl|br] via f16 MFMA. Block=256 (4 waves), 16 nodes/block.
__global__ __launch_bounds__(256) void transform_kernel(
        const __half* __restrict__ xh, const _Float16* __restrict__ wfrag,
        const float* __restrict__ bl, const float* __restrict__ br,
        __half* __restrict__ xl_h, __half* __restrict__ xr_h) {
    int w = threadIdx.x >> 6, lane = threadIdx.x & 63;
    int quad = lane >> 4, r16 = lane & 15;
    int m0 = blockIdx.x * 16;
    const _Float16* xrow = reinterpret_cast<const _Float16*>(xh) + (size_t)(m0 + r16) * D + quad * 8;
    half8 a[4];
    #pragma unroll
    for (int kt = 0; kt < 4; ++kt) a[kt] = *reinterpret_cast<const half8*>(xrow + kt * 32);
    f32x4 acc[4];
    #pragma unroll
    for (int nt = 0; nt < 4; ++nt) { f32x4 z = {0.f, 0.f, 0.f, 0.f}; acc[nt] = z; }
    #pragma unroll
    for (int nt = 0; nt < 4; ++nt) {
        int ntile = w * 4 + nt;
        #pragma unroll
        for (int kt = 0; kt < 4; ++kt) {
            half8 b = *reinterpret_cast<const half8*>(
                wfrag + ((size_t)(kt * 16 + ntile) * 64 + lane) * 8);
            acc[nt] = __builtin_amdgcn_mfma_f32_16x16x32_f16(a[kt], b, acc[nt], 0, 0, 0);
        }
    }
    #pragma unroll
    for (int nt = 0; nt < 4; ++nt) {
        int n = (w * 4 + nt) * 16 + r16;
        float bias = (n < 128) ? bl[n] : br[n - 128];
        #pragma unroll
        for (int r = 0; r < 4; ++r) {
            int node = m0 + quad * 4 + r;
            float v = acc[nt][r] + bias;
            if (n < 128) xl_h[(size_t)node * D + n] = __float2half_rn(v);
            else         xr_h[(size_t)node * D + (n - 128)] = __float2half_rn(v);
        }
    }
}

// One wave per node. Thread = 2 channels (packed fp16 math). Edge loop unrolled x8.
__global__ __launch_bounds__(64) void aggregate_kernel(
        const __half* __restrict__ xl_h, const __half* __restrict__ xr_h,
        const __half* __restrict__ loopm, const float* __restrict__ selff,
        const int* __restrict__ csr_off, const int* __restrict__ csr_src,
        const __half* __restrict__ csr_ea,
        const _Float16* __restrict__ Mh, const float* __restrict__ cfold,
        const float* __restrict__ att, const float* __restrict__ gbias,
        const float* __restrict__ bn_gamma, const float* __restrict__ bn_beta,
        __half* __restrict__ xout) {
    int n = blockIdx.x;
    int t = threadIdx.x;             // lane in wave
    int c0 = t * 2;                  // channels c0, c0+1; head = t>>3 (8 lanes/head)
    const char* xlb = reinterpret_cast<const char*>(xl_h);
    int lb = t << 2;                 // lane byte offset within a row (2 ch * 2 B)
    h2v attp = pkrtz(att[c0] * LOG2E, att[c0 + 1] * LOG2E);
    H4 m0u, m1u;
    m0u.f4 = *reinterpret_cast<const float4*>(Mh + (size_t)c0 * 8);
    m1u.f4 = *reinterpret_cast<const float4*>(Mh + (size_t)(c0 + 1) * 8);
    float cf0 = cfold[c0], cf1 = cfold[c0 + 1];
    h2v xrp = *reinterpret_cast<const h2v*>(xr_h + (size_t)n * D + c0);
    h2v xlp = *reinterpret_cast<const h2v*>(xl_h + (size_t)n * D + c0);
    const h2v c02 = {(_Float16)0.2f, (_Float16)0.2f};

    // self loop (edge attr = per-node mean of incoming raw attrs, fp16)
    H4 lau;
    lau.f4 = *reinterpret_cast<const float4*>(loopm + (size_t)n * 8);
    float sf = selff[n];
    float ep0 = cf0 * sf, ep1 = cf1 * sf;
    #pragma unroll
    for (int k = 0; k < 4; ++k) { ep0 = FDOT2(lau.h[k], m0u.h[k], ep0); ep1 = FDOT2(lau.h[k], m1u.h[k], ep1); }
    {
        f2v xlf = __builtin_convertvector(xlp, f2v);
        f2v xrf = __builtin_convertvector(xrp, f2v);
        float z0 = xlf[0] + xrf[0] + ep0; z0 = fmaxf(z0, 0.2f * z0);
        float z1 = xlf[1] + xrf[1] + ep1; z1 = fmaxf(z1, 0.2f * z1);
        ep0 = FDOT2(pkrtz(z0, z1), attp, 0.0f);
    }
    float m = red8(ep0);
    float denom = 1.0f;
    h2v acc = xlp;

    // scalar loop bounds (wave-uniform)
    int beg = __builtin_amdgcn_readfirstlane(csr_off[n]);
    int end = __builtin_amdgcn_readfirstlane(csr_off[n + 1]);
    for (int base = beg; base < end; base += 64) {
        int cnt = end - base; if (cnt > 64) cnt = 64;
        int sreg = (t < cnt) ? csr_src[base + t] : 0;   // coalesced; byte row offsets
        int i = 0;
        for (; i + 8 <= cnt; i += 8) {
            int off[8];
            #pragma unroll
            for (int k = 0; k < 8; ++k) off[k] = __shfl(sreg, i + k);
            h2v g[8];
            #pragma unroll
            for (int k = 0; k < 8; ++k) g[k] = *reinterpret_cast<const h2v*>(xlb + off[k] + lb);
            H4 eu[8];
            #pragma unroll
            for (int k = 0; k < 8; ++k)
                eu[k].f4 = *reinterpret_cast<const float4*>(csr_ea + (size_t)(base + i + k) * 8);
            float l[8];
            #pragma unroll
            for (int k = 0; k < 8; ++k) {
                float p0 = cf0, p1 = cf1;
                #pragma unroll
                for (int j = 0; j < 4; ++j) {
                    p0 = FDOT2(eu[k].h[j], m0u.h[j], p0);
                    p1 = FDOT2(eu[k].h[j], m1u.h[j], p1);
                }
                h2v z = g[k] + xrp + pkrtz(p0, p1);
                z = hmax2(z, z * c02);
                l[k] = red8(FDOT2(z, attp, 0.0f));
            }
            float gm = fmaxf(fmaxf(fmaxf(l[0], l[1]), fmaxf(l[2], l[3])),
                             fmaxf(fmaxf(l[4], l[5]), fmaxf(l[6], l[7])));
            float nm = fmaxf(m, gm);
            float wo = __builtin_amdgcn_exp2f(m - nm);
            float w[8];
            #pragma unroll
            for (int k = 0; k < 8; ++k) w[k] = __builtin_amdgcn_exp2f(l[k] - nm);
            denom = denom * wo + ((w[0] + w[1]) + (w[2] + w[3])) + ((w[4] + w[5]) + (w[6] + w[7]));
            acc = acc * pkrtz(wo, wo);
            #pragma unroll
            for (int k = 0; k < 8; ++k) acc = hfma2(pkrtz(w[k], w[k]), g[k], acc);
            m = nm;
        }
        for (; i + 4 <= cnt; i += 4) {
            int off[4];
            #pragma unroll
            for (int k = 0; k < 4; ++k) off[k] = __shfl(sreg, i + k);
            h2v g[4];
            #pragma unroll
            for (int k = 0; k < 4; ++k) g[k] = *reinterpret_cast<const h2v*>(xlb + off[k] + lb);
            H4 eu[4];
            #pragma unroll
            for (int k = 0; k < 4; ++k)
                eu[k].f4 = *reinterpret_cast<const float4*>(csr_ea + (size_t)(base + i + k) * 8);
            float l[4];
            #pragma unroll
            for (int k = 0; k < 4; ++k) {
                float p0 = cf0, p1 = cf1;
                #pragma unroll
                for (int j = 0; j < 4; ++j) {
                    p0 = FDOT2(eu[k].h[j], m0u.h[j], p0);
                    p1 = FDOT2(eu[k].h[j], m1u.h[j], p1);
                }
                h2v z = g[k] + xrp + pkrtz(p0, p1);
                z = hmax2(z, z * c02);
                l[k] = red8(FDOT2(z, attp, 0.0f));
            }
            float nm = fmaxf(m, fmaxf(fmaxf(l[0], l[1]), fmaxf(l[2], l[3])));
            float wo = __builtin_amdgcn_exp2f(m - nm);
            float w[4];
            #pragma unroll
            for (int k = 0; k < 4; ++k) w[k] = __builtin_amdgcn_exp2f(l[k] - nm);
            denom = denom * wo + (w[0] + w[1]) + (w[2] + w[3]);
            acc = acc * pkrtz(wo, wo);
            #pragma unroll
            for (int k = 0; k < 4; ++k) acc = hfma2(pkrtz(w[k], w[k]), g[k], acc);
            m = nm;
        }
        for (; i < cnt; ++i) {
            int o0 = __shfl(sreg, i);
            h2v g0 = *reinterpret_cast<const h2v*>(xlb + o0 + lb);
            H4 e0u;
            e0u.f4 = *reinterpret_cast<const float4*>(csr_ea + (size_t)(base + i) * 8);
            float p00 = cf0, p01 = cf1;
            #pragma unroll
            for (int k = 0; k < 4; ++k) { p00 = FDOT2(e0u.h[k], m0u.h[k], p00); p01 = FDOT2(e0u.h[k], m1u.h[k], p01); }
            h2v z0 = g0 + xrp + pkrtz(p00, p01);
            z0 = hmax2(z0, z0 * c02);
            float l0 = red8(FDOT2(z0, attp, 0.0f));
            float nm = fmaxf(m, l0);
            float wo = __builtin_amdgcn_exp2f(m - nm);
            float w0 = __builtin_amdgcn_exp2f(l0 - nm);
            denom = denom * wo + w0;
            acc = acc * pkrtz(wo, wo);
            acc = hfma2(pkrtz(w0, w0), g0, acc);
            m = nm;
        }
    }
    f2v accf = __builtin_convertvector(acc, f2v);
    float inv = 1.0f / denom;
    float h0 = accf[0] * inv + gbias[c0];
    float h1 = accf[1] * inv + gbias[c0 + 1];
    h0 = bn_gamma[c0] * h0 * 0.999995000037499813f + bn_beta[c0];
    h1 = bn_gamma[c0 + 1] * h1 * 0.999995000037499813f + bn_beta[c0 + 1];
    h0 = h0 > 0.f ? h0 : (__expf(h0) - 1.0f);
    h1 = h1 > 0.f ? h1 : (__expf(h1) - 1.0f);
    *reinterpret_cast<__half2*>(xout + (size_t)n * D + c0) = __floats2half2_rn(h0, h1);
}

__device__ __forceinline__ int lower_bound_dev(const int* a, int n, int v) {
    int lo = 0, hi = n;
    while (lo < hi) { int mid = (lo + hi) >> 1; if (a[mid] < v) lo = mid + 1; else hi = mid; }
    return lo;
}

__global__ __launch_bounds__(128) void headpool_kernel(
        const __half* __restrict__ xh, const int* __restrict__ batch,
        const float* __restrict__ hW, const float* __restrict__ hb,
        float* __restrict__ out) {
    __shared__ float lds[128];
    int g = blockIdx.x, t = threadIdx.x;
    int lo = lower_bound_dev(batch, N, g);
    int hi = lower_bound_dev(batch, N, g + 1);
    float s = 0.f;
    #pragma unroll 4
    for (int i = lo; i < hi; ++i) s += __half2float(xh[(size_t)i * D + t]);
    int c = hi - lo;
    lds[t] = s / (float)(c > 1 ? c : 1);
    __syncthreads();
    if (t < NC) {
        float p = hb[t];
        #pragma unroll 8
        for (int cc = 0; cc < D; ++cc) p += lds[cc] * hW[cc * NC + t];
        out[g * NC + t] = p;
    }
}

extern "C" void kernel_launch(void* const* d_in, const int* in_sizes, int n_in,
                              void* d_out, int out_size, void* d_ws, size_t ws_size,
                              hipStream_t stream) {
    const int*   x_nodes   = (const int*)  d_in[0];
    const int*   edge_src  = (const int*)  d_in[1];
    const int*   edge_dst  = (const int*)  d_in[2];
    const float* edge_attr = (const float*)d_in[3];
    const int*   batch     = (const int*)  d_in[4];
    const float* node_emb  = (const float*)d_in[5];
    const float* edge_W    = (const float*)d_in[6];
    const float* edge_b    = (const float*)d_in[7];
    const float* Wl        = (const float*)d_in[8];
    const float* bl        = (const float*)d_in[9];
    const float* Wr        = (const float*)d_in[10];
    const float* br        = (const float*)d_in[11];
    const float* We        = (const float*)d_in[12];
    const float* att       = (const float*)d_in[13];
    const float* gbias     = (const float*)d_in[14];
    const float* bn_gamma  = (const float*)d_in[15];
    const float* bn_beta   = (const float*)d_in[16];
    const float* head_W    = (const float*)d_in[17];
    const float* head_b    = (const float*)d_in[18];
    float* out = (float*)d_out;

    float* ws = (float*)d_ws;
    int*    cnt      = (int*)(ws + O_CNT);
    int*    csr_off  = (int*)(ws + O_CSROFF);
    int*    bsum     = (int*)(ws + O_BSUM);
    int*    myoff    = (int*)(ws + O_MYOFF);
    int*    rank     = (int*)(ws + O_RANK);
    int*    csr_src  = (int*)(ws + O_CSRSRC);
    __half* csr_ea   = (__half*)(ws + O_CSREA);
    _Float16* Mh     = (_Float16*)(ws + O_MH);
    float*  cfold    = ws + O_CFOLD;
    __half* loopm    = (__half*)(ws + O_LOOPM);
    float*  selff    = ws + O_SELFF;
    _Float16* wfrag  = (_Float16*)(ws + O_WFRAG);
    __half* xh   = (__half*)(ws + O_XH);
    __half* xl_h = (__half*)(ws + O_XLH);
    __half* xr_h = (__half*)(ws + O_XRH);

    hipMemsetAsync(cnt, 0, N * sizeof(int), stream);
    prep_kernel<<<PB_TOTAL, 256, 0, stream>>>(x_nodes, node_emb, xh,
                                              edge_src, edge_dst, cnt, myoff,
                                              Wl, Wr, wfrag, edge_W, edge_b, We, Mh, cfold);
    {
        int nb = (N + 1023) / 1024;   // 49
        scan1_kernel<<<nb, 256, 0, stream>>>(cnt, csr_off + 1, bsum);
        scan3_kernel<<<(N + 255) / 256, 256, 0, stream>>>(csr_off, bsum);
    }
    rank_fill_kernel<<<(E + 255) / 256, 256, 0, stream>>>(edge_dst, csr_off, myoff, rank);
    csr_build_kernel<<<(E + 255) / 256, 256, 0, stream>>>(rank, edge_src, edge_attr,
                                                          csr_off + N, csr_src, csr_ea);
    loopmean_kernel<<<(N * 8 + 255) / 256, 256, 0, stream>>>(csr_off, csr_ea, loopm, selff);
    for (int l = 0; l < L; ++l) {
        transform_kernel<<<N / 16, 256, 0, stream>>>(
            xh, wfrag + (size_t)l * 32768, bl + l * D, br + l * D, xl_h, xr_h);
        aggregate_kernel<<<N, 64, 0, stream>>>(
            xl_h, xr_h, loopm, selff, csr_off, csr_src, csr_ea,
            Mh + (size_t)l * D * 8, cfold + l * D, att + l * D, gbias + l * D,
            bn_gamma + l * D, bn_beta + l * D, xh);
    }
    headpool_kernel<<<G, 128, 0, stream>>>(xh, batch, head_W, head_b, out);

    (void)in_sizes; (void)n_in; (void)out_size; (void)ws_size;
}

// Round 13
// 507.506 us; speedup vs baseline: 1.1186x; 1.0125x over previous
//
#include <hip/hip_runtime.h>
#include <hip/hip_fp16.h>
#include <math.h>

static constexpr int N  = 50000;
static constexpr int E  = 800000;
static constexpr int G  = 512;
static constexpr int D  = 128;
static constexpr int EF = 8;
static constexpr int EE = 64;
static constexpr int L  = 4;
static constexpr int NC = 10;

typedef _Float16 half8 __attribute__((ext_vector_type(8)));
typedef _Float16 h2v  __attribute__((ext_vector_type(2)));
typedef float f2v __attribute__((ext_vector_type(2)));
typedef float f32x4 __attribute__((ext_vector_type(4)));

union H4 { float4 f4; f32x4 v4; h2v h[4]; };

#if __has_builtin(__builtin_amdgcn_fdot2)
#define FDOT2(a, b, c) __builtin_amdgcn_fdot2((a), (b), (c), false)
#else
#define FDOT2(a, b, c) ((float)(a)[0]*(float)(b)[0] + (float)(a)[1]*(float)(b)[1] + (c))
#endif

__device__ __forceinline__ h2v pkrtz(float a, float b) {
    return (h2v)__builtin_amdgcn_cvt_pkrtz(a, b);
}
__device__ __forceinline__ h2v hmax2(h2v a, h2v b) {
#if __has_builtin(__builtin_elementwise_max)
    return __builtin_elementwise_max(a, b);
#else
    h2v r; r[0] = a[0] > b[0] ? a[0] : b[0]; r[1] = a[1] > b[1] ? a[1] : b[1]; return r;
#endif
}
__device__ __forceinline__ h2v hfma2(h2v a, h2v b, h2v c) {
#if __has_builtin(__builtin_elementwise_fma)
    return __builtin_elementwise_fma(a, b, c);
#else
    return a * b + c;
#endif
}
// sum over 8-lane head group (lanes t, t^1, t^2, t^4) via DPP — no LDS traffic
__device__ __forceinline__ float red8(float v) {
#if __has_builtin(__builtin_amdgcn_update_dpp)
    v += __builtin_bit_cast(float, __builtin_amdgcn_update_dpp(
            0, __builtin_bit_cast(int, v), 0xB1, 0xF, 0xF, true));   // quad_perm xor1
    v += __builtin_bit_cast(float, __builtin_amdgcn_update_dpp(
            0, __builtin_bit_cast(int, v), 0x4E, 0xF, 0xF, true));   // quad_perm xor2
    v += __builtin_bit_cast(float, __builtin_amdgcn_update_dpp(
            0, __builtin_bit_cast(int, v), 0x141, 0xF, 0xF, true));  // row_half_mirror
#else
    v += __shfl_xor(v, 1); v += __shfl_xor(v, 2); v += __shfl_xor(v, 4);
#endif
    return v;
}

#define LOG2E 1.44269504088896340736f

static constexpr size_t pad64(size_t w){ return (w + 63) & ~size_t(63); }
// workspace layout in 4-byte words; cnt is zeroed by hipMemsetAsync
static constexpr size_t O_CNT     = 0;                               // N ints
static constexpr size_t O_CSROFF  = pad64(N);                        // N+1 ints
static constexpr size_t O_BSUM    = O_CSROFF + pad64(N+1);           // 64 ints
static constexpr size_t O_MYOFF   = O_BSUM + 64;                     // E ints
static constexpr size_t O_RANK    = O_MYOFF + pad64(E);              // E ints
static constexpr size_t O_CSRSRC  = O_RANK + pad64(E);               // E ints (row BYTE offsets)
static constexpr size_t O_CSREA   = O_CSRSRC + pad64(E);             // E*8 halfs = E*4 words
static constexpr size_t O_MH      = O_CSREA + pad64((size_t)E*4);    // L*D*8 halfs
static constexpr size_t O_CFOLD   = O_MH + pad64((size_t)L*512);     // L*D f32
static constexpr size_t O_LOOPM   = O_CFOLD + pad64(L*D);            // N*8 halfs
static constexpr size_t O_SELFF   = O_LOOPM + pad64((size_t)N*4);    // N f32
static constexpr size_t O_WFRAG   = O_SELFF + pad64(N);              // L*32768 halfs
static constexpr size_t O_XH      = O_WFRAG + pad64((size_t)L*16384);// N*D halfs
static constexpr size_t O_XLH     = O_XH  + pad64((size_t)N*64);
static constexpr size_t O_XRH     = O_XLH + pad64((size_t)N*64);

// prep grid partition (256-thread blocks) — FOLD first so it overlaps the wide parts
static constexpr int PB_FOLD = L;                             // 4
static constexpr int PB_ECNT = E / 256;                       // 3125
static constexpr int PB_WCVT = (L * 32768) / 256;             // 512
static constexpr int PB_EMB  = (N * D) / 256;                 // 25000
static constexpr int PB_TOTAL = PB_FOLD + PB_ECNT + PB_WCVT + PB_EMB;

// fused: fold (edge proj, fp16) | edge-degree+slot | wcvt (fragment weights) | embed (fp16)
__global__ __launch_bounds__(256) void prep_kernel(
        const int* __restrict__ xn, const float* __restrict__ emb, __half* __restrict__ xh,
        const int* __restrict__ esrc, const int* __restrict__ edst,
        int* __restrict__ cnt, int* __restrict__ myoff,
        const float* __restrict__ Wl, const float* __restrict__ Wr, _Float16* __restrict__ wfrag,
        const float* __restrict__ edge_W, const float* __restrict__ edge_b,
        const float* __restrict__ We, _Float16* __restrict__ Mh, float* __restrict__ cfold) {
    int bid = blockIdx.x, t = threadIdx.x;
    if (bid < PB_FOLD) {
        int l = bid;                               // 4 blocks, scheduled first
        if (t >= 128) return;
        const float* Wel = We + (size_t)l * EE * D;
        float s[EF];
        #pragma unroll
        for (int j = 0; j < EF; ++j) s[j] = 0.f;
        float sb = 0.f;
        for (int k = 0; k < EE; ++k) {             // k-outer: 64 coalesced loads, 8-way ILP
            float wv = Wel[k * D + t];
            #pragma unroll
            for (int j = 0; j < EF; ++j) s[j] += edge_W[j * EE + k] * wv;
            sb += edge_b[k] * wv;
        }
        #pragma unroll
        for (int j = 0; j < EF; ++j) Mh[((size_t)l * D + t) * 8 + j] = (_Float16)s[j];
        cfold[l * D + t] = sb;
    } else if (bid < PB_FOLD + PB_ECNT) {
        int e = (bid - PB_FOLD) * 256 + t;         // one edge per thread
        int s = esrc[e], d = edst[e];
        myoff[e] = (s == d) ? -1 : atomicAdd(&cnt[d], 1);
    } else if (bid < PB_FOLD + PB_ECNT + PB_WCVT) {
        int i = (bid - PB_FOLD - PB_ECNT) * 256 + t; // L*32768
        int j    = i & 7;
        int lane = (i >> 3) & 63;
        int nt   = (i >> 9) & 15;
        int kt   = (i >> 13) & 3;
        int l    = i >> 15;
        int k = kt * 32 + (lane >> 4) * 8 + j;
        int n = nt * 16 + (lane & 15);
        float v = (n < 128) ? Wl[((size_t)l * D + k) * D + n]
                            : Wr[((size_t)l * D + k) * D + (n - 128)];
        wfrag[i] = (_Float16)v;
    } else {
        int i = (bid - PB_FOLD - PB_ECNT - PB_WCVT) * 256 + t;  // N*D
        int n = i >> 7, c = i & 127;
        xh[i] = __float2half_rn(emb[xn[n] * D + c]);
    }
}

__global__ void scan1_kernel(const int* __restrict__ cnt, int* __restrict__ out /*=csr_off+1*/,
                             int* __restrict__ bsum) {
    __shared__ int lds[256];
    int b = blockIdx.x, t = threadIdx.x;
    int base = b * 1024 + t * 4;
    int v[4]; int s = 0;
    #pragma unroll
    for (int k = 0; k < 4; ++k) { int idx = base + k; v[k] = (idx < N) ? cnt[idx] : 0; s += v[k]; }
    lds[t] = s; __syncthreads();
    for (int off = 1; off < 256; off <<= 1) {
        int add = (t >= off) ? lds[t - off] : 0;
        __syncthreads();
        lds[t] += add;
        __syncthreads();
    }
    int run = (t > 0) ? lds[t - 1] : 0;
    #pragma unroll
    for (int k = 0; k < 4; ++k) { run += v[k]; int idx = base + k; if (idx < N) out[idx] = run; }
    if (t == 255) bsum[b] = lds[255];
}

__global__ void scan3_kernel(int* __restrict__ csr_off, const int* __restrict__ bsum) {
    int i = blockIdx.x * blockDim.x + threadIdx.x;
    if (i == 0) csr_off[0] = 0;
    if (i >= N) return;
    int b = i >> 10;
    int add = 0;
    for (int k = 0; k < b; ++k) add += bsum[k];
    csr_off[1 + i] += add;
}

// scattered write of 4B rank only (no atomics)
__global__ void rank_fill_kernel(const int* __restrict__ dst, const int* __restrict__ csr_off,
                                 const int* __restrict__ myoff, int* __restrict__ rank) {
    int e = blockIdx.x * blockDim.x + threadIdx.x;
    if (e >= E) return;
    int mo = myoff[e];
    if (mo < 0) return;
    rank[csr_off[dst[e]] + mo] = e;
}

// coalesced heavy-stream build (random reads, sequential writes)
__global__ void csr_build_kernel(const int* __restrict__ rank, const int* __restrict__ src,
                                 const float* __restrict__ eattr, const int* __restrict__ total,
                                 int* __restrict__ csr_src, __half* __restrict__ csr_ea) {
    int pos = blockIdx.x * blockDim.x + threadIdx.x;
    if (pos >= *total) return;
    int e = rank[pos];
    csr_src[pos] = src[e] << 8;   // byte offset of row e's source (128 ch * 2 B)
    const float4* p = reinterpret_cast<const float4*>(eattr + (size_t)e * 8);
    float4 a = p[0], b = p[1];
    H4 h;
    h.h[0] = pkrtz(a.x, a.y); h.h[1] = pkrtz(a.z, a.w);
    h.h[2] = pkrtz(b.x, b.y); h.h[3] = pkrtz(b.z, b.w);
    *reinterpret_cast<f32x4*>(csr_ea + (size_t)pos * 8) = h.v4;
}

__global__ void loopmean_kernel(const int* __restrict__ csr_off, const __half* __restrict__ csr_ea,
                                __half* __restrict__ loopm, float* __restrict__ selff) {
    int i = blockIdx.x * blockDim.x + threadIdx.x;   // N*8
    int n = i >> 3, j = i & 7;
    if (n >= N) return;
    int beg = csr_off[n], end = csr_off[n + 1];
    float s = 0.f;
    for (int idx = beg; idx < end; ++idx) s += __half2float(csr_ea[(size_t)idx * 8 + j]);
    int c = end - beg;
    loopm[(size_t)n * 8 + j] = __float2half_rn(s / (float)(c > 1 ? c : 1));
    if (j == 0) selff[n] = (c > 0) ? 1.0f : 0.0f;
}

// [xl|xr] = x @ [Wl|Wr] + [bl|br] via f16 MFMA. Block=256 (4 waves), 16 nodes/block.
__global__ __launch_bounds__(256) void transform_kernel(
        const __half* __restrict__ xh, const _Float16* __restrict__ wfrag,
        const float* __restrict__ bl, const float* __restrict__ br,
        __half* __restrict__ xl_h, __half* __restrict__ xr_h) {
    int w = threadIdx.x >> 6, lane = threadIdx.x & 63;
    int quad = lane >> 4, r16 = lane & 15;
    int m0 = blockIdx.x * 16;
    const _Float16* xrow = reinterpret_cast<const _Float16*>(xh) + (size_t)(m0 + r16) * D + quad * 8;
    half8 a[4];
    #pragma unroll
    for (int kt = 0; kt < 4; ++kt) a[kt] = *reinterpret_cast<const half8*>(xrow + kt * 32);
    f32x4 acc[4];
    #pragma unroll
    for (int nt = 0; nt < 4; ++nt) { f32x4 z = {0.f, 0.f, 0.f, 0.f}; acc[nt] = z; }
    #pragma unroll
    for (int nt = 0; nt < 4; ++nt) {
        int ntile = w * 4 + nt;
        #pragma unroll
        for (int kt = 0; kt < 4; ++kt) {
            half8 b = *reinterpret_cast<const half8*>(
                wfrag + ((size_t)(kt * 16 + ntile) * 64 + lane) * 8);
            acc[nt] = __builtin_amdgcn_mfma_f32_16x16x32_f16(a[kt], b, acc[nt], 0, 0, 0);
        }
    }
    #pragma unroll
    for (int nt = 0; nt < 4; ++nt) {
        int n = (w * 4 + nt) * 16 + r16;
        float bias = (n < 128) ? bl[n] : br[n - 128];
        #pragma unroll
        for (int r = 0; r < 4; ++r) {
            int node = m0 + quad * 4 + r;
            float v = acc[nt][r] + bias;
            if (n < 128) xl_h[(size_t)node * D + n] = __float2half_rn(v);
            else         xr_h[(size_t)node * D + (n - 128)] = __float2half_rn(v);
        }
    }
}

// One wave per node. Thread = 2 channels (packed fp16 math). Edge loop unrolled x8.
__global__ __launch_bounds__(64) void aggregate_kernel(
        const __half* __restrict__ xl_h, const __half* __restrict__ xr_h,
        const __half* __restrict__ loopm, const float* __restrict__ selff,
        const int* __restrict__ csr_off, const int* __restrict__ csr_src,
        const __half* __restrict__ csr_ea,
        const _Float16* __restrict__ Mh, const float* __restrict__ cfold,
        const float* __restrict__ att, const float* __restrict__ gbias,
        const float* __restrict__ bn_gamma, const float* __restrict__ bn_beta,
        __half* __restrict__ xout) {
    int n = blockIdx.x;
    int t = threadIdx.x;             // lane in wave
    int c0 = t * 2;                  // channels c0, c0+1; head = t>>3 (8 lanes/head)
    const char* xlb = reinterpret_cast<const char*>(xl_h);
    int lb = t << 2;                 // lane byte offset within a row (2 ch * 2 B)
    h2v attp = pkrtz(att[c0] * LOG2E, att[c0 + 1] * LOG2E);
    H4 m0u, m1u;
    m0u.f4 = *reinterpret_cast<const float4*>(Mh + (size_t)c0 * 8);
    m1u.f4 = *reinterpret_cast<const float4*>(Mh + (size_t)(c0 + 1) * 8);
    float cf0 = cfold[c0], cf1 = cfold[c0 + 1];
    h2v xrp = *reinterpret_cast<const h2v*>(xr_h + (size_t)n * D + c0);
    h2v xlp = *reinterpret_cast<const h2v*>(xl_h + (size_t)n * D + c0);
    const h2v c02 = {(_Float16)0.2f, (_Float16)0.2f};

    // self loop (edge attr = per-node mean of incoming raw attrs, fp16)
    H4 lau;
    lau.f4 = *reinterpret_cast<const float4*>(loopm + (size_t)n * 8);
    float sf = selff[n];
    float ep0 = cf0 * sf, ep1 = cf1 * sf;
    #pragma unroll
    for (int k = 0; k < 4; ++k) { ep0 = FDOT2(lau.h[k], m0u.h[k], ep0); ep1 = FDOT2(lau.h[k], m1u.h[k], ep1); }
    {
        f2v xlf = __builtin_convertvector(xlp, f2v);
        f2v xrf = __builtin_convertvector(xrp, f2v);
        float z0 = xlf[0] + xrf[0] + ep0; z0 = fmaxf(z0, 0.2f * z0);
        float z1 = xlf[1] + xrf[1] + ep1; z1 = fmaxf(z1, 0.2f * z1);
        ep0 = FDOT2(pkrtz(z0, z1), attp, 0.0f);
    }
    float m = red8(ep0);
    float denom = 1.0f;
    h2v acc = xlp;

    // scalar loop bounds (wave-uniform)
    int beg = __builtin_amdgcn_readfirstlane(csr_off[n]);
    int end = __builtin_amdgcn_readfirstlane(csr_off[n + 1]);
    for (int base = beg; base < end; base += 64) {
        int cnt = end - base; if (cnt > 64) cnt = 64;
        int sreg = (t < cnt) ? csr_src[base + t] : 0;   // coalesced; byte row offsets
        int i = 0;
        for (; i + 8 <= cnt; i += 8) {
            int off[8];
            #pragma unroll
            for (int k = 0; k < 8; ++k) off[k] = __shfl(sreg, i + k);
            h2v g[8];
            #pragma unroll
            for (int k = 0; k < 8; ++k) g[k] = *reinterpret_cast<const h2v*>(xlb + off[k] + lb);
            H4 eu[8];
            #pragma unroll
            for (int k = 0; k < 8; ++k)
                eu[k].f4 = *reinterpret_cast<const float4*>(csr_ea + (size_t)(base + i + k) * 8);
            float l[8];
            #pragma unroll
            for (int k = 0; k < 8; ++k) {
                float p0 = cf0, p1 = cf1;
                #pragma unroll
                for (int j = 0; j < 4; ++j) {
                    p0 = FDOT2(eu[k].h[j], m0u.h[j], p0);
                    p1 = FDOT2(eu[k].h[j], m1u.h[j], p1);
                }
                h2v z = g[k] + xrp + pkrtz(p0, p1);
                z = hmax2(z, z * c02);
                l[k] = red8(FDOT2(z, attp, 0.0f));
            }
            float gm = fmaxf(fmaxf(fmaxf(l[0], l[1]), fmaxf(l[2], l[3])),
                             fmaxf(fmaxf(l[4], l[5]), fmaxf(l[6], l[7])));
            float nm = fmaxf(m, gm);
            float wo = __builtin_amdgcn_exp2f(m - nm);
            float w[8];
            #pragma unroll
            for (int k = 0; k < 8; ++k) w[k] = __builtin_amdgcn_exp2f(l[k] - nm);
            denom = denom * wo + ((w[0] + w[1]) + (w[2] + w[3])) + ((w[4] + w[5]) + (w[6] + w[7]));
            acc = acc * pkrtz(wo, wo);
            #pragma unroll
            for (int k = 0; k < 8; ++k) acc = hfma2(pkrtz(w[k], w[k]), g[k], acc);
            m = nm;
        }
        for (; i + 4 <= cnt; i += 4) {
            int off[4];
            #pragma unroll
            for (int k = 0; k < 4; ++k) off[k] = __shfl(sreg, i + k);
            h2v g[4];
            #pragma unroll
            for (int k = 0; k < 4; ++k) g[k] = *reinterpret_cast<const h2v*>(xlb + off[k] + lb);
            H4 eu[4];
            #pragma unroll
            for (int k = 0; k < 4; ++k)
                eu[k].f4 = *reinterpret_cast<const float4*>(csr_ea + (size_t)(base + i + k) * 8);
            float l[4];
            #pragma unroll
            for (int k = 0; k < 4; ++k) {
                float p0 = cf0, p1 = cf1;
                #pragma unroll
                for (int j = 0; j < 4; ++j) {
                    p0 = FDOT2(eu[k].h[j], m0u.h[j], p0);
                    p1 = FDOT2(eu[k].h[j], m1u.h[j], p1);
                }
                h2v z = g[k] + xrp + pkrtz(p0, p1);
                z = hmax2(z, z * c02);
                l[k] = red8(FDOT2(z, attp, 0.0f));
            }
            float nm = fmaxf(m, fmaxf(fmaxf(l[0], l[1]), fmaxf(l[2], l[3])));
            float wo = __builtin_amdgcn_exp2f(m - nm);
            float w[4];
            #pragma unroll
            for (int k = 0; k < 4; ++k) w[k] = __builtin_amdgcn_exp2f(l[k] - nm);
            denom = denom * wo + (w[0] + w[1]) + (w[2] + w[3]);
            acc = acc * pkrtz(wo, wo);
            #pragma unroll
            for (int k = 0; k < 4; ++k) acc = hfma2(pkrtz(w[k], w[k]), g[k], acc);
            m = nm;
        }
        for (; i < cnt; ++i) {
            int o0 = __shfl(sreg, i);
            h2v g0 = *reinterpret_cast<const h2v*>(xlb + o0 + lb);
            H4 e0u;
            e0u.f4 = *reinterpret_cast<const float4*>(csr_ea + (size_t)(base + i) * 8);
            float p00 = cf0, p01 = cf1;
            #pragma unroll
            for (int k = 0; k < 4; ++k) { p00 = FDOT2(e0u.h[k], m0u.h[k], p00); p01 = FDOT2(e0u.h[k], m1u.h[k], p01); }
            h2v z0 = g0 + xrp + pkrtz(p00, p01);
            z0 = hmax2(z0, z0 * c02);
            float l0 = red8(FDOT2(z0, attp, 0.0f));
            float nm = fmaxf(m, l0);
            float wo = __builtin_amdgcn_exp2f(m - nm);
            float w0 = __builtin_amdgcn_exp2f(l0 - nm);
            denom = denom * wo + w0;
            acc = acc * pkrtz(wo, wo);
            acc = hfma2(pkrtz(w0, w0), g0, acc);
            m = nm;
        }
    }
    f2v accf = __builtin_convertvector(acc, f2v);
    float inv = 1.0f / denom;
    float h0 = accf[0] * inv + gbias[c0];
    float h1 = accf[1] * inv + gbias[c0 + 1];
    h0 = bn_gamma[c0] * h0 * 0.999995000037499813f + bn_beta[c0];
    h1 = bn_gamma[c0 + 1] * h1 * 0.999995000037499813f + bn_beta[c0 + 1];
    h0 = h0 > 0.f ? h0 : (__expf(h0) - 1.0f);
    h1 = h1 > 0.f ? h1 : (__expf(h1) - 1.0f);
    *reinterpret_cast<__half2*>(xout + (size_t)n * D + c0) = __floats2half2_rn(h0, h1);
}

__device__ __forceinline__ int lower_bound_dev(const int* a, int n, int v) {
    int lo = 0, hi = n;
    while (lo < hi) { int mid = (lo + hi) >> 1; if (a[mid] < v) lo = mid + 1; else hi = mid; }
    return lo;
}

__global__ __launch_bounds__(128) void headpool_kernel(
        const __half* __restrict__ xh, const int* __restrict__ batch,
        const float* __restrict__ hW, const float* __restrict__ hb,
        float* __restrict__ out) {
    __shared__ float lds[128];
    int g = blockIdx.x, t = threadIdx.x;
    int lo = lower_bound_dev(batch, N, g);
    int hi = lower_bound_dev(batch, N, g + 1);
    float s = 0.f;
    #pragma unroll 4
    for (int i = lo; i < hi; ++i) s += __half2float(xh[(size_t)i * D + t]);
    int c = hi - lo;
    lds[t] = s / (float)(c > 1 ? c : 1);
    __syncthreads();
    if (t < NC) {
        float p = hb[t];
        #pragma unroll 8
        for (int cc = 0; cc < D; ++cc) p += lds[cc] * hW[cc * NC + t];
        out[g * NC + t] = p;
    }
}

extern "C" void kernel_launch(void* const* d_in, const int* in_sizes, int n_in,
                              void* d_out, int out_size, void* d_ws, size_t ws_size,
                              hipStream_t stream) {
    const int*   x_nodes   = (const int*)  d_in[0];
    const int*   edge_src  = (const int*)  d_in[1];
    const int*   edge_dst  = (const int*)  d_in[2];
    const float* edge_attr = (const float*)d_in[3];
    const int*   batch     = (const int*)  d_in[4];
    const float* node_emb  = (const float*)d_in[5];
    const float* edge_W    = (const float*)d_in[6];
    const float* edge_b    = (const float*)d_in[7];
    const float* Wl        = (const float*)d_in[8];
    const float* bl        = (const float*)d_in[9];
    const float* Wr        = (const float*)d_in[10];
    const float* br        = (const float*)d_in[11];
    const float* We        = (const float*)d_in[12];
    const float* att       = (const float*)d_in[13];
    const float* gbias     = (const float*)d_in[14];
    const float* bn_gamma  = (const float*)d_in[15];
    const float* bn_beta   = (const float*)d_in[16];
    const float* head_W    = (const float*)d_in[17];
    const float* head_b    = (const float*)d_in[18];
    float* out = (float*)d_out;

    float* ws = (float*)d_ws;
    int*    cnt      = (int*)(ws + O_CNT);
    int*    csr_off  = (int*)(ws + O_CSROFF);
    int*    bsum     = (int*)(ws + O_BSUM);
    int*    myoff    = (int*)(ws + O_MYOFF);
    int*    rank     = (int*)(ws + O_RANK);
    int*    csr_src  = (int*)(ws + O_CSRSRC);
    __half* csr_ea   = (__half*)(ws + O_CSREA);
    _Float16* Mh     = (_Float16*)(ws + O_MH);
    float*  cfold    = ws + O_CFOLD;
    __half* loopm    = (__half*)(ws + O_LOOPM);
    float*  selff    = ws + O_SELFF;
    _Float16* wfrag  = (_Float16*)(ws + O_WFRAG);
    __half* xh   = (__half*)(ws + O_XH);
    __half* xl_h = (__half*)(ws + O_XLH);
    __half* xr_h = (__half*)(ws + O_XRH);

    hipMemsetAsync(cnt, 0, N * sizeof(int), stream);
    prep_kernel<<<PB_TOTAL, 256, 0, stream>>>(x_nodes, node_emb, xh,
                                              edge_src, edge_dst, cnt, myoff,
                                              Wl, Wr, wfrag, edge_W, edge_b, We, Mh, cfold);
    {
        int nb = (N + 1023) / 1024;   // 49
        scan1_kernel<<<nb, 256, 0, stream>>>(cnt, csr_off + 1, bsum);
        scan3_kernel<<<(N + 255) / 256, 256, 0, stream>>>(csr_off, bsum);
    }
    rank_fill_kernel<<<(E + 255) / 256, 256, 0, stream>>>(edge_dst, csr_off, myoff, rank);
    csr_build_kernel<<<(E + 255) / 256, 256, 0, stream>>>(rank, edge_src, edge_attr,
                                                          csr_off + N, csr_src, csr_ea);
    loopmean_kernel<<<(N * 8 + 255) / 256, 256, 0, stream>>>(csr_off, csr_ea, loopm, selff);
    for (int l = 0; l < L; ++l) {
        transform_kernel<<<N / 16, 256, 0, stream>>>(
            xh, wfrag + (size_t)l * 32768, bl + l * D, br + l * D, xl_h, xr_h);
        aggregate_kernel<<<N, 64, 0, stream>>>(
            xl_h, xr_h, loopm, selff, csr_off, csr_src, csr_ea,
            Mh + (size_t)l * D * 8, cfold + l * D, att + l * D, gbias + l * D,
            bn_gamma + l * D, bn_beta + l * D, xh);
    }
    headpool_kernel<<<G, 128, 0, stream>>>(xh, batch, head_W, head_b, out);

    (void)in_sizes; (void)n_in; (void)out_size; (void)ws_size;
}